// Round 7
// baseline (104.897 us; speedup 1.0000x reference)
//
#include <hip/hip_runtime.h>
#include <hip/hip_bf16.h>

#define LN_EPS 1e-5f
typedef __attribute__((ext_vector_type(8))) short short8v;
typedef __attribute__((ext_vector_type(4))) short short4v;
typedef __attribute__((ext_vector_type(4))) float f32x4;
typedef __hip_bfloat16 bf16;

#define GW_STR 1088   // Gw row stride (k), 1024 data + 16 P + 48 pad

__device__ inline float wred_sum(float v) {
#pragma unroll
  for (int off = 1; off < 64; off <<= 1) v += __shfl_xor(v, off, 64);
  return v;
}
__device__ inline float b2f(short s) {
  return __uint_as_float(((unsigned)(unsigned short)s) << 16);
}
__device__ inline short f2bs(float x) {
  union { bf16 h; short s; } u; u.h = __float2bfloat16(x); return u.s;
}
__device__ inline float rbf(float x) {
  return __bfloat162float(__float2bfloat16(x));
}

// ---- fused: LN(q,k,v) -> bf16 rows  |  W_in/W_out f32 -> bf16 ---------------
__global__ __launch_bounds__(256) void lncvt_kernel(
    const float* __restrict__ q, const float* __restrict__ k,
    const float* __restrict__ v,
    const float* __restrict__ g, const float* __restrict__ bln,
    const float* __restrict__ Wi, const float* __restrict__ Wo,
    bf16* __restrict__ abf, bf16* __restrict__ Wib, bf16* __restrict__ Wob) {
  int bid = blockIdx.x, tid = threadIdx.x;
  if (bid < 3072) {
    int wave = tid >> 6, lane = tid & 63;
    int grow = bid * 4 + wave;                // 0..12287
    int tensor = grow >> 12, row = grow & 4095;
    const float* src = tensor == 0 ? q : (tensor == 1 ? k : v);
    const float4* p = (const float4*)(src + (size_t)row * 512 + lane * 8);
    float4 a = p[0], b = p[1];
    float s  = a.x + a.y + a.z + a.w + b.x + b.y + b.z + b.w;
    float ss = a.x*a.x + a.y*a.y + a.z*a.z + a.w*a.w
             + b.x*b.x + b.y*b.y + b.z*b.z + b.w*b.w;
    s = wred_sum(s);
    ss = wred_sum(ss);
    float m = s * (1.f / 512.f);
    float r = rsqrtf(ss * (1.f / 512.f) - m * m + LN_EPS);
    float4 g0 = *(const float4*)(g + lane * 8);
    float4 g1 = *(const float4*)(g + lane * 8 + 4);
    float4 b0 = *(const float4*)(bln + lane * 8);
    float4 b1 = *(const float4*)(bln + lane * 8 + 4);
    short8v t;
    t[0] = f2bs((a.x - m) * r * g0.x + b0.x);
    t[1] = f2bs((a.y - m) * r * g0.y + b0.y);
    t[2] = f2bs((a.z - m) * r * g0.z + b0.z);
    t[3] = f2bs((a.w - m) * r * g0.w + b0.w);
    t[4] = f2bs((b.x - m) * r * g1.x + b1.x);
    t[5] = f2bs((b.y - m) * r * g1.y + b1.y);
    t[6] = f2bs((b.z - m) * r * g1.z + b1.z);
    t[7] = f2bs((b.w - m) * r * g1.w + b1.w);
    *(short8v*)(abf + (size_t)grow * 512 + lane * 8) = t;
  } else {
    int e0 = ((bid - 3072) * 256 + tid) * 8;
    float4 a = *(const float4*)(Wi + e0);
    float4 b = *(const float4*)(Wi + e0 + 4);
    short8v t;
    t[0] = f2bs(a.x); t[1] = f2bs(a.y); t[2] = f2bs(a.z); t[3] = f2bs(a.w);
    t[4] = f2bs(b.x); t[5] = f2bs(b.y); t[6] = f2bs(b.z); t[7] = f2bs(b.w);
    *(short8v*)(Wib + e0) = t;
    a = *(const float4*)(Wo + e0);
    b = *(const float4*)(Wo + e0 + 4);
    t[0] = f2bs(a.x); t[1] = f2bs(a.y); t[2] = f2bs(a.z); t[3] = f2bs(a.w);
    t[4] = f2bs(b.x); t[5] = f2bs(b.y); t[6] = f2bs(b.z); t[7] = f2bs(b.w);
    *(short8v*)(Wob + e0) = t;
  }
}

// ---- proj: 64x128-tile GEMM abf @ Wib^T + full epilogue (R5 structure) ------
__global__ __launch_bounds__(256) void proj_kernel(
    const bf16* __restrict__ Asrc, const bf16* __restrict__ Wb,
    bf16* __restrict__ f_q, bf16* __restrict__ fkt, bf16* __restrict__ fkh,
    bf16* __restrict__ fvt,
    float* __restrict__ rn, float* __restrict__ mn, float* __restrict__ vr,
    float* __restrict__ gp) {
  __shared__ bf16 As[64 * 72];
  __shared__ bf16 Bs[128 * 72];
  __shared__ float gpbuf[4][128];
  int tid = threadIdx.x;
  int bj = blockIdx.x, bi = blockIdx.y;
  int row0 = bi * 64;
  int wv = tid >> 6, l = tid & 63, fr = l & 15, lq = l >> 4;
  int sarow = tid >> 2, sakc = (tid & 3) * 16;
  int sbrow = tid >> 1, sbkc = (tid & 1) * 32;
  f32x4 acc[8];
#pragma unroll
  for (int j = 0; j < 8; ++j)
#pragma unroll
    for (int e = 0; e < 4; ++e) acc[j][e] = 0.f;

  for (int ks = 0; ks < 512; ks += 64) {
    {
      const bf16* src = Asrc + (size_t)(row0 + sarow) * 512 + ks + sakc;
      *(short8v*)&As[sarow * 72 + sakc]     = *(const short8v*)src;
      *(short8v*)&As[sarow * 72 + sakc + 8] = *(const short8v*)(src + 8);
    }
    {
      const bf16* src = Wb + (size_t)(bj * 128 + sbrow) * 512 + ks + sbkc;
#pragma unroll
      for (int c = 0; c < 4; ++c)
        *(short8v*)&Bs[sbrow * 72 + sbkc + c * 8] = *(const short8v*)(src + c * 8);
    }
    __syncthreads();
#pragma unroll
    for (int kk = 0; kk < 64; kk += 32) {
      short8v af = *(const short8v*)&As[(wv * 16 + fr) * 72 + kk + lq * 8];
#pragma unroll
      for (int j = 0; j < 8; ++j) {
        short8v bv = *(const short8v*)&Bs[(j * 16 + fr) * 72 + kk + lq * 8];
        acc[j] = __builtin_amdgcn_mfma_f32_16x16x32_bf16(af, bv, acc[j], 0, 0, 0);
      }
    }
    __syncthreads();
  }

  // ---- epilogue ----
  int tensor = bi >> 6, rb = bi & 63;
  int b = rb >> 4, n0 = (rb & 15) * 64;
  int nbase = n0 + wv * 16 + lq * 4;          // +rr
  if (tensor == 2) {
#pragma unroll
    for (int j = 0; j < 8; ++j) {
      int h = bj * 2 + (j >> 2), hb = h * 4 + b;
      int dv = (j & 3) * 16 + fr;
      short4v t;
#pragma unroll
      for (int rr = 0; rr < 4; ++rr) t[rr] = f2bs(acc[j][rr]);
      *(short4v*)(fvt + (size_t)(hb * 64 + dv) * 1024 + nbase) = t;
    }
    return;
  }
  float vb[8][4];
#pragma unroll
  for (int j = 0; j < 8; ++j)
#pragma unroll
    for (int rr = 0; rr < 4; ++rr) vb[j][rr] = rbf(acc[j][rr]);

#pragma unroll
  for (int hh = 0; hh < 2; ++hh) {
    int h = bj * 2 + hh, hb = h * 4 + b;
    float sr[4], s2[4];
#pragma unroll
    for (int rr = 0; rr < 4; ++rr) {
      float s = 0.f, ss = 0.f;
#pragma unroll
      for (int jj = 0; jj < 4; ++jj) {
        float x = vb[hh * 4 + jj][rr];
        s += x; ss += x * x;
      }
#pragma unroll
      for (int off = 1; off < 16; off <<= 1) {
        s += __shfl_xor(s, off, 64);
        ss += __shfl_xor(ss, off, 64);
      }
      sr[rr] = s; s2[rr] = ss;
    }
    if (tensor == 0) {
#pragma unroll
      for (int jj = 0; jj < 4; ++jj) {
        int d = jj * 16 + fr;
#pragma unroll
        for (int rr = 0; rr < 4; ++rr)
          f_q[(size_t)(b * 1024 + nbase + rr) * 512 + h * 64 + d] =
              __float2bfloat16(acc[hh * 4 + jj][rr]);
      }
      if (fr == 0)
#pragma unroll
        for (int rr = 0; rr < 4; ++rr) {
          size_t idx = (size_t)hb * 1024 + nbase + rr;
          float mean = sr[rr] * (1.f / 64.f);
          rn[idx] = rsqrtf(s2[rr]);
          mn[idx] = mean;
          vr[idx] = (s2[rr] - 64.f * mean * mean) * (1.f / 63.f);
        }
    } else {
      float rnv[4];
#pragma unroll
      for (int rr = 0; rr < 4; ++rr) rnv[rr] = rsqrtf(s2[rr]);
#pragma unroll
      for (int jj = 0; jj < 4; ++jj) {
        int dk = jj * 16 + fr;
        short4v tp, th;
#pragma unroll
        for (int rr = 0; rr < 4; ++rr) {
          tp[rr] = f2bs(acc[hh * 4 + jj][rr]);
          th[rr] = f2bs(vb[hh * 4 + jj][rr] * rnv[rr]);
        }
        size_t off = (size_t)(hb * 64 + dk) * 1024 + nbase;
        *(short4v*)(fkt + off) = tp;
        *(short4v*)(fkh + off) = th;
      }
      if (fr == 0)
#pragma unroll
        for (int rr = 0; rr < 4; ++rr) {
          size_t idx = 32768 + (size_t)hb * 1024 + nbase + rr;
          float mean = sr[rr] * (1.f / 64.f);
          mn[idx] = mean;
          vr[idx] = (s2[rr] - 64.f * mean * mean) * (1.f / 63.f);
        }
    }
  }
#pragma unroll
  for (int j = 0; j < 8; ++j) {
    float c = 0.f;
#pragma unroll
    for (int rr = 0; rr < 4; ++rr) c += vb[j][rr];
    c += __shfl_xor(c, 16, 64);
    c += __shfl_xor(c, 32, 64);
    if (lq == 0) gpbuf[wv][j * 16 + fr] = c;
  }
  __syncthreads();
  if (tid < 128)
    gp[(size_t)(tensor * 64 + rb) * 512 + bj * 128 + tid] =
        gpbuf[0][tid] + gpbuf[1][tid] + gpbuf[2][tid] + gpbuf[3][tid];
}

// ---------------- aux: full KtV -> A_T | rank1 | mlp -------------------------
__global__ __launch_bounds__(256) void aux_kernel(
    const bf16* __restrict__ fvt, const bf16* __restrict__ fkt,
    const bf16* __restrict__ fkh,
    const float* __restrict__ mn, const float* __restrict__ vr,
    const float* __restrict__ gp,
    const float* __restrict__ W1, const float* __restrict__ b1,
    const float* __restrict__ lg, const float* __restrict__ lb,
    const float* __restrict__ W2, const float* __restrict__ b2,
    bf16* __restrict__ A_T, float* __restrict__ kvm, float* __restrict__ kvv,
    float* __restrict__ wts) {
  __shared__ float sh[2560];
  int bid = blockIdx.x, tid = threadIdx.x;
  int wv = tid >> 6, l = tid & 63, fr = l & 15, lq = l >> 4;
  if (bid < 32) {
    int hb = bid;
    f32x4 apl[4], aht[4];
#pragma unroll
    for (int j = 0; j < 4; ++j)
#pragma unroll
      for (int e = 0; e < 4; ++e) { apl[j][e] = 0.f; aht[j][e] = 0.f; }
    size_t arow = (size_t)(hb * 64 + wv * 16 + fr) * 1024;
#pragma unroll 4
    for (int m0 = 0; m0 < 1024; m0 += 32) {
      short8v av = *(const short8v*)(fvt + arow + m0 + lq * 8);
#pragma unroll
      for (int j = 0; j < 4; ++j) {
        size_t brow = (size_t)(hb * 64 + j * 16 + fr) * 1024 + m0 + lq * 8;
        short8v bp = *(const short8v*)(fkt + brow);
        short8v bh = *(const short8v*)(fkh + brow);
        apl[j] = __builtin_amdgcn_mfma_f32_16x16x32_bf16(av, bp, apl[j], 0, 0, 0);
        aht[j] = __builtin_amdgcn_mfma_f32_16x16x32_bf16(av, bh, aht[j], 0, 0, 0);
      }
    }
#pragma unroll
    for (int j = 0; j < 4; ++j)
#pragma unroll
      for (int rr = 0; rr < 4; ++rr) {
        int dv = wv * 16 + lq * 4 + rr, dk = j * 16 + fr;
        A_T[(size_t)hb * 8192 + dv * 64 + dk] = __float2bfloat16(apl[j][rr]);
        A_T[(size_t)hb * 8192 + 4096 + dv * 64 + dk] = __float2bfloat16(aht[j][rr]);
      }
  } else if (bid < 64) {
    int hb = bid - 32;
    float* kmL = sh; float* kvL = sh + 1024; float* red = sh + 2048;
    for (int i = tid; i < 1024; i += 256) {
      kmL[i] = mn[32768 + hb * 1024 + i];
      kvL[i] = vr[32768 + hb * 1024 + i];
    }
    __syncthreads();
    int dv = tid >> 2, seg = tid & 3;
    float am = 0.f, av = 0.f;
    size_t rowb = (size_t)(hb * 64 + dv) * 1024 + seg * 256;
    for (int i = 0; i < 256; i += 8) {
      short8v vv = *(const short8v*)(fvt + rowb + i);
#pragma unroll
      for (int e = 0; e < 8; ++e) {
        float f = b2f(vv[e]);
        am += kmL[seg * 256 + i + e] * f;
        av += kvL[seg * 256 + i + e] * f;
      }
    }
    red[dv * 4 + seg] = am;
    red[256 + dv * 4 + seg] = av;
    __syncthreads();
    if (tid < 64) {
      kvm[hb * 64 + tid] = red[tid * 4] + red[tid * 4 + 1] + red[tid * 4 + 2] + red[tid * 4 + 3];
      kvv[hb * 64 + tid] = red[256 + tid * 4] + red[256 + tid * 4 + 1] +
                           red[256 + tid * 4 + 2] + red[256 + tid * 4 + 3];
    }
  } else {
    float* fqv = sh; float* fkv = sh + 512;
    for (int c = tid; c < 512; c += 256) {
      float sq = 0.f, sk = 0.f;
      for (int p = 0; p < 64; ++p) {
        sq += gp[(size_t)p * 512 + c];
        sk += gp[(size_t)(64 + p) * 512 + c];
      }
      fqv[c] = sq * (1.f / 4096.f);
      fkv[c] = sk * (1.f / 4096.f);
    }
    __syncthreads();
#pragma unroll
    for (int hh = 0; hh < 2; ++hh) {
      int h = hh * 4 + wv, j = l;
      float pre = b1[j];
      for (int i = 0; i < 64; ++i) pre += fqv[h * 64 + i] * W1[j * 128 + i];
      for (int i = 0; i < 64; ++i) pre += fkv[h * 64 + i] * W1[j * 128 + 64 + i];
      float s = wred_sum(pre);
      float ss = wred_sum(pre * pre);
      float mean = s * (1.f / 64.f);
      float var = ss * (1.f / 64.f) - mean * mean;
      float hdn = (pre - mean) * rsqrtf(var + LN_EPS) * lg[j] + lb[j];
      hdn = fmaxf(hdn, 0.f);
      float l0 = wred_sum(hdn * W2[0 * 64 + j]) + b2[0];
      float l1 = wred_sum(hdn * W2[1 * 64 + j]) + b2[1];
      float l2 = wred_sum(hdn * W2[2 * 64 + j]) + b2[2];
      float mx = fmaxf(l0, fmaxf(l1, l2));
      float e0 = __expf(l0 - mx), e1 = __expf(l1 - mx), e2 = __expf(l2 - mx);
      float inv = 1.f / (e0 + e1 + e2);
      if (j == 0) {
        wts[h * 3 + 0] = e0 * inv;
        wts[h * 3 + 1] = e1 * inv;
        wts[h * 3 + 2] = e2 * inv;
      }
    }
  }
}

// ---- gprep: Gw[b][c][k] = fold A_T/kvm/kvv through Wob ----------------------
//   k in [0,512):    Ghat[c][h*64+dk] = sum_dv A_ht[dv][dk] * Wob[c][h*64+dv]
//   k in [512,1024): Gpl  (same with A_pl)
//   k = 1024+2h / +1: c1 = kvm@Wob_h^T, c2 = kvv@Wob_h^T;  [1040,1088) = 0
__global__ __launch_bounds__(256) void gprep_kernel(
    const bf16* __restrict__ A_T, const bf16* __restrict__ Wob,
    const float* __restrict__ kvm, const float* __restrict__ kvv,
    bf16* __restrict__ Gw) {
  __shared__ bf16 Tpl[64 * 72];
  __shared__ bf16 Tht[64 * 72];
  int bid = blockIdx.x;            // 128: (hb, cb)
  int hb = bid >> 2, cb = bid & 3;
  int h = hb >> 2, b = hb & 3;
  int tid = threadIdx.x;
  int wv = tid >> 6, l = tid & 63, fr = l & 15, lq = l >> 4;
  {  // stage A tiles transposed: T[dk][dv]
    int dv = tid >> 2, dkc = (tid & 3) * 16;
    const bf16* s0 = A_T + (size_t)hb * 8192 + dv * 64 + dkc;
#pragma unroll
    for (int i = 0; i < 16; ++i) {
      Tpl[(dkc + i) * 72 + dv] = s0[i];
      Tht[(dkc + i) * 72 + dv] = s0[4096 + i];
    }
  }
  __syncthreads();
  // GEMM: rows c (wave -> 32), cols dk (64), K = dv (64)
  f32x4 aht_[2][4], apl_[2][4];
#pragma unroll
  for (int i = 0; i < 2; ++i)
#pragma unroll
    for (int j = 0; j < 4; ++j)
#pragma unroll
      for (int e = 0; e < 4; ++e) { aht_[i][j][e] = 0.f; apl_[i][j][e] = 0.f; }
#pragma unroll
  for (int kk = 0; kk < 64; kk += 32) {
    short8v a0 = *(const short8v*)(Wob + (size_t)(cb * 128 + wv * 32 + fr) * 512 + h * 64 + kk + lq * 8);
    short8v a1 = *(const short8v*)(Wob + (size_t)(cb * 128 + wv * 32 + 16 + fr) * 512 + h * 64 + kk + lq * 8);
#pragma unroll
    for (int j = 0; j < 4; ++j) {
      short8v bh = *(const short8v*)&Tht[(j * 16 + fr) * 72 + kk + lq * 8];
      short8v bp = *(const short8v*)&Tpl[(j * 16 + fr) * 72 + kk + lq * 8];
      aht_[0][j] = __builtin_amdgcn_mfma_f32_16x16x32_bf16(a0, bh, aht_[0][j], 0, 0, 0);
      aht_[1][j] = __builtin_amdgcn_mfma_f32_16x16x32_bf16(a1, bh, aht_[1][j], 0, 0, 0);
      apl_[0][j] = __builtin_amdgcn_mfma_f32_16x16x32_bf16(a0, bp, apl_[0][j], 0, 0, 0);
      apl_[1][j] = __builtin_amdgcn_mfma_f32_16x16x32_bf16(a1, bp, apl_[1][j], 0, 0, 0);
    }
  }
#pragma unroll
  for (int i = 0; i < 2; ++i)
#pragma unroll
    for (int j = 0; j < 4; ++j)
#pragma unroll
      for (int rr = 0; rr < 4; ++rr) {
        int c = cb * 128 + wv * 32 + i * 16 + lq * 4 + rr;
        int dk = j * 16 + fr;
        size_t base = (size_t)(b * 512 + c) * GW_STR;
        Gw[base + h * 64 + dk]       = __float2bfloat16(aht_[i][j][rr]);
        Gw[base + 512 + h * 64 + dk] = __float2bfloat16(apl_[i][j][rr]);
      }
  // c1/c2 rows + zero padding
  {
    int cl = tid >> 1, half = tid & 1;
    float p1 = 0.f, p2 = 0.f;
    const bf16* wrow = Wob + (size_t)(cb * 128 + cl) * 512 + h * 64 + half * 32;
#pragma unroll
    for (int dv = 0; dv < 32; ++dv) {
      float w = b2f(((const short*)wrow)[dv]);
      p1 += kvm[hb * 64 + half * 32 + dv] * w;
      p2 += kvv[hb * 64 + half * 32 + dv] * w;
    }
    p1 += __shfl_xor(p1, 1, 64);
    p2 += __shfl_xor(p2, 1, 64);
    if (half == 0) {
      size_t base = (size_t)(b * 512 + cb * 128 + cl) * GW_STR;
      Gw[base + 1024 + 2 * h]     = __float2bfloat16(p1);
      Gw[base + 1024 + 2 * h + 1] = __float2bfloat16(p2);
    }
  }
  if (h == 0) {
    for (int z = tid; z < 128 * 48; z += 256) {
      int cl = z / 48, kz = 1040 + z % 48;
      Gw[(size_t)(b * 512 + cb * 128 + cl) * GW_STR + kz] = __float2bfloat16(0.f);
    }
  }
}

// ---- applyout: out = [w0*qrn*Q | f1*Q | P] @ Gw^T + b_out  (K=1088) ---------
__global__ __launch_bounds__(256) void applyout_kernel(
    const bf16* __restrict__ f_q, const bf16* __restrict__ Gw,
    const float* __restrict__ rn, const float* __restrict__ mn,
    const float* __restrict__ vr, const float* __restrict__ wts,
    const float* __restrict__ bias, float* __restrict__ out) {
  __shared__ bf16 As[64 * 72];
  __shared__ bf16 Bs[128 * 72];
  __shared__ float sA[8][64], sPm[8][64], sPv[8][64];
  __shared__ float f1s[8];
  int tid = threadIdx.x;
  int bj = blockIdx.x, bi = blockIdx.y;     // (4, 64)
  int row0 = bi * 64;
  int b = bi >> 4, n0 = (bi & 15) * 64;
  int wv = tid >> 6, l = tid & 63, fr = l & 15, lq = l >> 4;
  if (tid < 8) f1s[tid] = wts[tid * 3 + 1] * (1.f / 64.f);
  for (int idx = tid; idx < 512; idx += 256) {
    int h = idx >> 6, row = idx & 63;
    int hb = h * 4 + b;
    float w0 = wts[h * 3 + 0], w1 = wts[h * 3 + 1], w2 = wts[h * 3 + 2];
    size_t base = (size_t)hb * 1024 + n0 + row;
    sA[h][row]  = w0 * rn[base];
    sPm[h][row] = -w1 * mn[base];
    sPv[h][row] = w2 * (1.f / 64.f) * vr[base];
  }
  __syncthreads();

  int sarow = tid >> 2, sakc = (tid & 3) * 16;
  int sbrow = tid >> 1, sbkc = (tid & 1) * 32;
  f32x4 acc[8];
#pragma unroll
  for (int j = 0; j < 8; ++j)
#pragma unroll
    for (int e = 0; e < 4; ++e) acc[j][e] = 0.f;

  for (int s = 0; s < 17; ++s) {
    {  // A' staging
      short t16[16];
      if (s < 16) {
        int hh = s & 7;
        float sc = (s < 8) ? sA[hh][sarow] : f1s[hh];
        const bf16* src = f_q + (size_t)(b * 1024 + n0 + sarow) * 512 + hh * 64 + sakc;
        short8v v0 = *(const short8v*)src;
        short8v v1 = *(const short8v*)(src + 8);
#pragma unroll
        for (int i = 0; i < 8; ++i) {
          t16[i]     = f2bs(sc * b2f(v0[i]));
          t16[i + 8] = f2bs(sc * b2f(v1[i]));
        }
      } else {
#pragma unroll
        for (int i = 0; i < 16; ++i) {
          int kloc = sakc + i;
          float val = 0.f;
          if (kloc < 16) {
            int hh = kloc >> 1;
            val = (kloc & 1) ? sPv[hh][sarow] : sPm[hh][sarow];
          }
          t16[i] = f2bs(val);
        }
      }
      *(short8v*)&As[sarow * 72 + sakc]     = *(short8v*)&t16[0];
      *(short8v*)&As[sarow * 72 + sakc + 8] = *(short8v*)&t16[8];
    }
    {  // B staging from Gw
      const bf16* src = Gw + (size_t)(b * 512 + bj * 128 + sbrow) * GW_STR + s * 64 + sbkc;
#pragma unroll
      for (int c = 0; c < 4; ++c)
        *(short8v*)&Bs[sbrow * 72 + sbkc + c * 8] = *(const short8v*)(src + c * 8);
    }
    __syncthreads();
#pragma unroll
    for (int kk = 0; kk < 64; kk += 32) {
      short8v af = *(const short8v*)&As[(wv * 16 + fr) * 72 + kk + lq * 8];
#pragma unroll
      for (int j = 0; j < 8; ++j) {
        short8v bv = *(const short8v*)&Bs[(j * 16 + fr) * 72 + kk + lq * 8];
        acc[j] = __builtin_amdgcn_mfma_f32_16x16x32_bf16(af, bv, acc[j], 0, 0, 0);
      }
    }
    __syncthreads();
  }
#pragma unroll
  for (int j = 0; j < 8; ++j) {
    int col = bj * 128 + j * 16 + fr;
    float bvv = bias[col];
#pragma unroll
    for (int rr = 0; rr < 4; ++rr)
      out[(size_t)(row0 + wv * 16 + lq * 4 + rr) * 512 + col] = acc[j][rr] + bvv;
  }
}

extern "C" void kernel_launch(void* const* d_in, const int* in_sizes, int n_in,
                              void* d_out, int out_size, void* d_ws, size_t ws_size,
                              hipStream_t stream) {
  const float* q     = (const float*)d_in[0];
  const float* k     = (const float*)d_in[1];
  const float* v     = (const float*)d_in[2];
  const float* ln_g  = (const float*)d_in[3];
  const float* ln_b  = (const float*)d_in[4];
  const float* W_in  = (const float*)d_in[5];
  const float* W_out = (const float*)d_in[6];
  const float* b_out = (const float*)d_in[7];
  const float* wp_W1 = (const float*)d_in[8];
  const float* wp_b1 = (const float*)d_in[9];
  const float* wp_lg = (const float*)d_in[10];
  const float* wp_lb = (const float*)d_in[11];
  const float* wp_W2 = (const float*)d_in[12];
  const float* wp_b2 = (const float*)d_in[13];
  float* out = (float*)d_out;

  char* w8 = (char*)d_ws;
  bf16* abf   = (bf16*)(w8);                              // 12 MB
  bf16* f_q   = (bf16*)(w8 + (12u << 20));                // 4 MB
  bf16* fkt   = (bf16*)(w8 + (16u << 20));                // 4 MB
  bf16* fkh   = (bf16*)(w8 + (20u << 20));                // 4 MB
  bf16* fvt   = (bf16*)(w8 + (24u << 20));                // 4 MB
  bf16* Gw    = (bf16*)(w8 + (28u << 20));                // 4.46 MB
  bf16* A_T   = (bf16*)(w8 + (33u << 20));                // 512 KB
  bf16* Wib   = (bf16*)(w8 + (33u << 20) + (512u << 10)); // 512 KB
  bf16* Wob   = (bf16*)(w8 + (34u << 20));                // 512 KB
  float* fb   = (float*)(w8 + (34u << 20) + (512u << 10));
  float* rn  = fb;            // 32768
  float* mn  = fb + 32768;    // 65536 (q, k)
  float* vr  = fb + 98304;    // 65536
  float* gp  = fb + 163840;   // 65536 ([2*64][512])
  float* kvm = fb + 229376;   // 2048
  float* kvv = fb + 231424;   // 2048
  float* wts = fb + 233472;   // 24

  lncvt_kernel<<<3200, 256, 0, stream>>>(q, k, v, ln_g, ln_b, W_in, W_out,
                                         abf, Wib, Wob);
  proj_kernel<<<dim3(4, 192), 256, 0, stream>>>(
      abf, Wib, f_q, fkt, fkh, fvt, rn, mn, vr, gp);
  aux_kernel<<<65, 256, 0, stream>>>(
      fvt, fkt, fkh, mn, vr, gp, wp_W1, wp_b1, wp_lg, wp_lb, wp_W2, wp_b2,
      A_T, kvm, kvv, wts);
  gprep_kernel<<<128, 256, 0, stream>>>(A_T, Wob, kvm, kvv, Gw);
  applyout_kernel<<<dim3(4, 64), 256, 0, stream>>>(
      f_q, Gw, rn, mn, vr, wts, b_out, out);
}

// Round 8
// 82.896 us; speedup vs baseline: 1.2654x; 1.2654x over previous
//
#include <hip/hip_runtime.h>
#include <hip/hip_bf16.h>

#define LN_EPS 1e-5f
typedef __attribute__((ext_vector_type(8))) short short8v;
typedef __attribute__((ext_vector_type(4))) short short4v;
typedef __attribute__((ext_vector_type(4))) float f32x4;
typedef __hip_bfloat16 bf16;

__device__ inline float wred_sum(float v) {
#pragma unroll
  for (int off = 1; off < 64; off <<= 1) v += __shfl_xor(v, off, 64);
  return v;
}
__device__ inline float b2f(short s) {
  return __uint_as_float(((unsigned)(unsigned short)s) << 16);
}
__device__ inline short f2bs(float x) {
  union { bf16 h; short s; } u; u.h = __float2bfloat16(x); return u.s;
}
__device__ inline float rbf(float x) {
  return __bfloat162float(__float2bfloat16(x));
}

// ---- fused: LN(q,k,v) -> bf16 rows  |  W_in/W_out f32 -> bf16 ---------------
__global__ __launch_bounds__(256) void lncvt_kernel(
    const float* __restrict__ q, const float* __restrict__ k,
    const float* __restrict__ v,
    const float* __restrict__ g, const float* __restrict__ bln,
    const float* __restrict__ Wi, const float* __restrict__ Wo,
    bf16* __restrict__ abf, bf16* __restrict__ Wib, bf16* __restrict__ Wob) {
  int bid = blockIdx.x, tid = threadIdx.x;
  if (bid < 3072) {
    int wave = tid >> 6, lane = tid & 63;
    int grow = bid * 4 + wave;                // 0..12287
    int tensor = grow >> 12, row = grow & 4095;
    const float* src = tensor == 0 ? q : (tensor == 1 ? k : v);
    const float4* p = (const float4*)(src + (size_t)row * 512 + lane * 8);
    float4 a = p[0], b = p[1];
    float s  = a.x + a.y + a.z + a.w + b.x + b.y + b.z + b.w;
    float ss = a.x*a.x + a.y*a.y + a.z*a.z + a.w*a.w
             + b.x*b.x + b.y*b.y + b.z*b.z + b.w*b.w;
    s = wred_sum(s);
    ss = wred_sum(ss);
    float m = s * (1.f / 512.f);
    float r = rsqrtf(ss * (1.f / 512.f) - m * m + LN_EPS);
    float4 g0 = *(const float4*)(g + lane * 8);
    float4 g1 = *(const float4*)(g + lane * 8 + 4);
    float4 b0 = *(const float4*)(bln + lane * 8);
    float4 b1 = *(const float4*)(bln + lane * 8 + 4);
    short8v t;
    t[0] = f2bs((a.x - m) * r * g0.x + b0.x);
    t[1] = f2bs((a.y - m) * r * g0.y + b0.y);
    t[2] = f2bs((a.z - m) * r * g0.z + b0.z);
    t[3] = f2bs((a.w - m) * r * g0.w + b0.w);
    t[4] = f2bs((b.x - m) * r * g1.x + b1.x);
    t[5] = f2bs((b.y - m) * r * g1.y + b1.y);
    t[6] = f2bs((b.z - m) * r * g1.z + b1.z);
    t[7] = f2bs((b.w - m) * r * g1.w + b1.w);
    *(short8v*)(abf + (size_t)grow * 512 + lane * 8) = t;
  } else {
    int e0 = ((bid - 3072) * 256 + tid) * 8;
    float4 a = *(const float4*)(Wi + e0);
    float4 b = *(const float4*)(Wi + e0 + 4);
    short8v t;
    t[0] = f2bs(a.x); t[1] = f2bs(a.y); t[2] = f2bs(a.z); t[3] = f2bs(a.w);
    t[4] = f2bs(b.x); t[5] = f2bs(b.y); t[6] = f2bs(b.z); t[7] = f2bs(b.w);
    *(short8v*)(Wib + e0) = t;
    a = *(const float4*)(Wo + e0);
    b = *(const float4*)(Wo + e0 + 4);
    t[0] = f2bs(a.x); t[1] = f2bs(a.y); t[2] = f2bs(a.z); t[3] = f2bs(a.w);
    t[4] = f2bs(b.x); t[5] = f2bs(b.y); t[6] = f2bs(b.z); t[7] = f2bs(b.w);
    *(short8v*)(Wob + e0) = t;
  }
}

// ---- proj: 64x128-tile GEMM abf @ Wib^T + full epilogue ---------------------
// Staging via global_load_lds (linear LDS dest, XOR-swizzled source+read).
__global__ __launch_bounds__(256) void proj_kernel(
    const bf16* __restrict__ Asrc, const bf16* __restrict__ Wb,
    bf16* __restrict__ f_q, bf16* __restrict__ fkt, bf16* __restrict__ fkh,
    bf16* __restrict__ fvt,
    float* __restrict__ rn, float* __restrict__ mn, float* __restrict__ vr,
    float* __restrict__ gp) {
  __shared__ __attribute__((aligned(16))) bf16 As[64 * 64];
  __shared__ __attribute__((aligned(16))) bf16 Bs[128 * 64];
  __shared__ float gpbuf[4][128];
  int tid = threadIdx.x;
  int bj = blockIdx.x, bi = blockIdx.y;
  int row0 = bi * 64;
  int wv = tid >> 6, l = tid & 63, fr = l & 15, lq = l >> 4;
  f32x4 acc[8];
#pragma unroll
  for (int j = 0; j < 8; ++j)
#pragma unroll
    for (int e = 0; e < 4; ++e) acc[j][e] = 0.f;

  // fragment read byte-cols (swizzled with row): c = kk*2 + lq*16
  int swz = (fr & 7) << 4;

  for (int ks = 0; ks < 512; ks += 64) {
    // A: 8 KB, 2 calls/wave. LDS byte off = wv*2048 + c*1024 + l*16
#pragma unroll
    for (int c = 0; c < 2; ++c) {
      int off = wv * 2048 + c * 1024 + l * 16;
      int ar = off >> 7;                   // row 0..63
      int sc = (off & 127) ^ ((ar & 7) << 4);
      const char* gsrc = (const char*)(Asrc + (size_t)(row0 + ar) * 512 + ks) + sc;
      __builtin_amdgcn_global_load_lds(gsrc, (char*)As + wv * 2048 + c * 1024, 16, 0, 0);
    }
    // B: 16 KB, 4 calls/wave
#pragma unroll
    for (int c = 0; c < 4; ++c) {
      int off = wv * 4096 + c * 1024 + l * 16;
      int br = off >> 7;                   // row 0..127
      int sc = (off & 127) ^ ((br & 7) << 4);
      const char* gsrc = (const char*)(Wb + (size_t)(bj * 128 + br) * 512 + ks) + sc;
      __builtin_amdgcn_global_load_lds(gsrc, (char*)Bs + wv * 4096 + c * 1024, 16, 0, 0);
    }
    __syncthreads();
#pragma unroll
    for (int kk = 0; kk < 64; kk += 32) {
      int cbyte = kk * 2 + lq * 16;
      int csw = cbyte ^ swz;
      short8v af = *(const short8v*)&As[(wv * 16 + fr) * 64 + (csw >> 1)];
#pragma unroll
      for (int j = 0; j < 8; ++j) {
        short8v bv = *(const short8v*)&Bs[(j * 16 + fr) * 64 + (csw >> 1)];
        acc[j] = __builtin_amdgcn_mfma_f32_16x16x32_bf16(af, bv, acc[j], 0, 0, 0);
      }
    }
    __syncthreads();
  }

  // ---- epilogue (identical to R5) ----
  int tensor = bi >> 6, rb = bi & 63;
  int b = rb >> 4, n0 = (rb & 15) * 64;
  int nbase = n0 + wv * 16 + lq * 4;          // +rr
  if (tensor == 2) {
#pragma unroll
    for (int j = 0; j < 8; ++j) {
      int h = bj * 2 + (j >> 2), hb = h * 4 + b;
      int dv = (j & 3) * 16 + fr;
      short4v t;
#pragma unroll
      for (int rr = 0; rr < 4; ++rr) t[rr] = f2bs(acc[j][rr]);
      *(short4v*)(fvt + (size_t)(hb * 64 + dv) * 1024 + nbase) = t;
    }
    return;
  }
  float vb[8][4];
#pragma unroll
  for (int j = 0; j < 8; ++j)
#pragma unroll
    for (int rr = 0; rr < 4; ++rr) vb[j][rr] = rbf(acc[j][rr]);

#pragma unroll
  for (int hh = 0; hh < 2; ++hh) {
    int h = bj * 2 + hh, hb = h * 4 + b;
    float sr[4], s2[4];
#pragma unroll
    for (int rr = 0; rr < 4; ++rr) {
      float s = 0.f, ss = 0.f;
#pragma unroll
      for (int jj = 0; jj < 4; ++jj) {
        float x = vb[hh * 4 + jj][rr];
        s += x; ss += x * x;
      }
#pragma unroll
      for (int off = 1; off < 16; off <<= 1) {
        s += __shfl_xor(s, off, 64);
        ss += __shfl_xor(ss, off, 64);
      }
      sr[rr] = s; s2[rr] = ss;
    }
    if (tensor == 0) {
#pragma unroll
      for (int jj = 0; jj < 4; ++jj) {
        int d = jj * 16 + fr;
#pragma unroll
        for (int rr = 0; rr < 4; ++rr)
          f_q[(size_t)(b * 1024 + nbase + rr) * 512 + h * 64 + d] =
              __float2bfloat16(acc[hh * 4 + jj][rr]);
      }
      if (fr == 0)
#pragma unroll
        for (int rr = 0; rr < 4; ++rr) {
          size_t idx = (size_t)hb * 1024 + nbase + rr;
          float mean = sr[rr] * (1.f / 64.f);
          rn[idx] = rsqrtf(s2[rr]);
          mn[idx] = mean;
          vr[idx] = (s2[rr] - 64.f * mean * mean) * (1.f / 63.f);
        }
    } else {
      float rnv[4];
#pragma unroll
      for (int rr = 0; rr < 4; ++rr) rnv[rr] = rsqrtf(s2[rr]);
#pragma unroll
      for (int jj = 0; jj < 4; ++jj) {
        int dk = jj * 16 + fr;
        short4v tp, th;
#pragma unroll
        for (int rr = 0; rr < 4; ++rr) {
          tp[rr] = f2bs(acc[hh * 4 + jj][rr]);
          th[rr] = f2bs(vb[hh * 4 + jj][rr] * rnv[rr]);
        }
        size_t off = (size_t)(hb * 64 + dk) * 1024 + nbase;
        *(short4v*)(fkt + off) = tp;
        *(short4v*)(fkh + off) = th;
      }
      if (fr == 0)
#pragma unroll
        for (int rr = 0; rr < 4; ++rr) {
          size_t idx = 32768 + (size_t)hb * 1024 + nbase + rr;
          float mean = sr[rr] * (1.f / 64.f);
          mn[idx] = mean;
          vr[idx] = (s2[rr] - 64.f * mean * mean) * (1.f / 63.f);
        }
    }
  }
#pragma unroll
  for (int j = 0; j < 8; ++j) {
    float c = 0.f;
#pragma unroll
    for (int rr = 0; rr < 4; ++rr) c += vb[j][rr];
    c += __shfl_xor(c, 16, 64);
    c += __shfl_xor(c, 32, 64);
    if (lq == 0) gpbuf[wv][j * 16 + fr] = c;
  }
  __syncthreads();
  if (tid < 128)
    gp[(size_t)(tensor * 64 + rb) * 512 + bj * 128 + tid] =
        gpbuf[0][tid] + gpbuf[1][tid] + gpbuf[2][tid] + gpbuf[3][tid];
}

// ---- outproj: 64x128-tile GEMM attnb @ Wob^T + bias -> f32 out --------------
__global__ __launch_bounds__(256) void outproj_kernel(
    const bf16* __restrict__ Ab, const bf16* __restrict__ Wb,
    const float* __restrict__ bias, float* __restrict__ out) {
  __shared__ __attribute__((aligned(16))) bf16 As[64 * 64];
  __shared__ __attribute__((aligned(16))) bf16 Bs[128 * 64];
  int tid = threadIdx.x;
  int bj = blockIdx.x, bi = blockIdx.y;
  int row0 = bi * 64;
  int wv = tid >> 6, l = tid & 63, fr = l & 15, lq = l >> 4;
  f32x4 acc[8];
#pragma unroll
  for (int j = 0; j < 8; ++j)
#pragma unroll
    for (int e = 0; e < 4; ++e) acc[j][e] = 0.f;

  int swz = (fr & 7) << 4;

  for (int ks = 0; ks < 512; ks += 64) {
#pragma unroll
    for (int c = 0; c < 2; ++c) {
      int off = wv * 2048 + c * 1024 + l * 16;
      int ar = off >> 7;
      int sc = (off & 127) ^ ((ar & 7) << 4);
      const char* gsrc = (const char*)(Ab + (size_t)(row0 + ar) * 512 + ks) + sc;
      __builtin_amdgcn_global_load_lds(gsrc, (char*)As + wv * 2048 + c * 1024, 16, 0, 0);
    }
#pragma unroll
    for (int c = 0; c < 4; ++c) {
      int off = wv * 4096 + c * 1024 + l * 16;
      int br = off >> 7;
      int sc = (off & 127) ^ ((br & 7) << 4);
      const char* gsrc = (const char*)(Wb + (size_t)(bj * 128 + br) * 512 + ks) + sc;
      __builtin_amdgcn_global_load_lds(gsrc, (char*)Bs + wv * 4096 + c * 1024, 16, 0, 0);
    }
    __syncthreads();
#pragma unroll
    for (int kk = 0; kk < 64; kk += 32) {
      int csw = (kk * 2 + lq * 16) ^ swz;
      short8v af = *(const short8v*)&As[(wv * 16 + fr) * 64 + (csw >> 1)];
#pragma unroll
      for (int j = 0; j < 8; ++j) {
        short8v bv = *(const short8v*)&Bs[(j * 16 + fr) * 64 + (csw >> 1)];
        acc[j] = __builtin_amdgcn_mfma_f32_16x16x32_bf16(af, bv, acc[j], 0, 0, 0);
      }
    }
    __syncthreads();
  }
#pragma unroll
  for (int j = 0; j < 8; ++j) {
    int col = bj * 128 + j * 16 + fr;
    float bvv = bias[col];
#pragma unroll
    for (int rr = 0; rr < 4; ++rr)
      out[(size_t)(row0 + wv * 16 + lq * 4 + rr) * 512 + col] = acc[j][rr] + bvv;
  }
}

// ---------------- aux: full KtV -> A_T | rank1 | mlp -------------------------
__global__ __launch_bounds__(256) void aux_kernel(
    const bf16* __restrict__ fvt, const bf16* __restrict__ fkt,
    const bf16* __restrict__ fkh,
    const float* __restrict__ mn, const float* __restrict__ vr,
    const float* __restrict__ gp,
    const float* __restrict__ W1, const float* __restrict__ b1,
    const float* __restrict__ lg, const float* __restrict__ lb,
    const float* __restrict__ W2, const float* __restrict__ b2,
    bf16* __restrict__ A_T, float* __restrict__ kvm, float* __restrict__ kvv,
    float* __restrict__ wts) {
  __shared__ float sh[2560];
  int bid = blockIdx.x, tid = threadIdx.x;
  int wv = tid >> 6, l = tid & 63, fr = l & 15, lq = l >> 4;
  if (bid < 32) {
    int hb = bid;
    f32x4 apl[4], aht[4];
#pragma unroll
    for (int j = 0; j < 4; ++j)
#pragma unroll
      for (int e = 0; e < 4; ++e) { apl[j][e] = 0.f; aht[j][e] = 0.f; }
    size_t arow = (size_t)(hb * 64 + wv * 16 + fr) * 1024;
#pragma unroll 4
    for (int m0 = 0; m0 < 1024; m0 += 32) {
      short8v av = *(const short8v*)(fvt + arow + m0 + lq * 8);
#pragma unroll
      for (int j = 0; j < 4; ++j) {
        size_t brow = (size_t)(hb * 64 + j * 16 + fr) * 1024 + m0 + lq * 8;
        short8v bp = *(const short8v*)(fkt + brow);
        short8v bh = *(const short8v*)(fkh + brow);
        apl[j] = __builtin_amdgcn_mfma_f32_16x16x32_bf16(av, bp, apl[j], 0, 0, 0);
        aht[j] = __builtin_amdgcn_mfma_f32_16x16x32_bf16(av, bh, aht[j], 0, 0, 0);
      }
    }
#pragma unroll
    for (int j = 0; j < 4; ++j)
#pragma unroll
      for (int rr = 0; rr < 4; ++rr) {
        int dv = wv * 16 + lq * 4 + rr, dk = j * 16 + fr;
        A_T[(size_t)hb * 8192 + dv * 64 + dk] = __float2bfloat16(apl[j][rr]);
        A_T[(size_t)hb * 8192 + 4096 + dv * 64 + dk] = __float2bfloat16(aht[j][rr]);
      }
  } else if (bid < 64) {
    int hb = bid - 32;
    float* kmL = sh; float* kvL = sh + 1024; float* red = sh + 2048;
    for (int i = tid; i < 1024; i += 256) {
      kmL[i] = mn[32768 + hb * 1024 + i];
      kvL[i] = vr[32768 + hb * 1024 + i];
    }
    __syncthreads();
    int dv = tid >> 2, seg = tid & 3;
    float am = 0.f, av = 0.f;
    size_t rowb = (size_t)(hb * 64 + dv) * 1024 + seg * 256;
    for (int i = 0; i < 256; i += 8) {
      short8v vv = *(const short8v*)(fvt + rowb + i);
#pragma unroll
      for (int e = 0; e < 8; ++e) {
        float f = b2f(vv[e]);
        am += kmL[seg * 256 + i + e] * f;
        av += kvL[seg * 256 + i + e] * f;
      }
    }
    red[dv * 4 + seg] = am;
    red[256 + dv * 4 + seg] = av;
    __syncthreads();
    if (tid < 64) {
      kvm[hb * 64 + tid] = red[tid * 4] + red[tid * 4 + 1] + red[tid * 4 + 2] + red[tid * 4 + 3];
      kvv[hb * 64 + tid] = red[256 + tid * 4] + red[256 + tid * 4 + 1] +
                           red[256 + tid * 4 + 2] + red[256 + tid * 4 + 3];
    }
  } else {
    float* fqv = sh; float* fkv = sh + 512;
    for (int c = tid; c < 512; c += 256) {
      float sq = 0.f, sk = 0.f;
      for (int p = 0; p < 64; ++p) {
        sq += gp[(size_t)p * 512 + c];
        sk += gp[(size_t)(64 + p) * 512 + c];
      }
      fqv[c] = sq * (1.f / 4096.f);
      fkv[c] = sk * (1.f / 4096.f);
    }
    __syncthreads();
#pragma unroll
    for (int hh = 0; hh < 2; ++hh) {
      int h = hh * 4 + wv, j = l;
      float pre = b1[j];
      for (int i = 0; i < 64; ++i) pre += fqv[h * 64 + i] * W1[j * 128 + i];
      for (int i = 0; i < 64; ++i) pre += fkv[h * 64 + i] * W1[j * 128 + 64 + i];
      float s = wred_sum(pre);
      float ss = wred_sum(pre * pre);
      float mean = s * (1.f / 64.f);
      float var = ss * (1.f / 64.f) - mean * mean;
      float hdn = (pre - mean) * rsqrtf(var + LN_EPS) * lg[j] + lb[j];
      hdn = fmaxf(hdn, 0.f);
      float l0 = wred_sum(hdn * W2[0 * 64 + j]) + b2[0];
      float l1 = wred_sum(hdn * W2[1 * 64 + j]) + b2[1];
      float l2 = wred_sum(hdn * W2[2 * 64 + j]) + b2[2];
      float mx = fmaxf(l0, fmaxf(l1, l2));
      float e0 = __expf(l0 - mx), e1 = __expf(l1 - mx), e2 = __expf(l2 - mx);
      float inv = 1.f / (e0 + e1 + e2);
      if (j == 0) {
        wts[h * 3 + 0] = e0 * inv;
        wts[h * 3 + 1] = e1 * inv;
        wts[h * 3 + 2] = e2 * inv;
      }
    }
  }
}

// ---------------- apply: out = w0*qrn*(Q@Ahat^T) + f1*(Q@Apl^T) + rank1 ------
__global__ __launch_bounds__(256) void apply_kernel(
    const bf16* __restrict__ f_q, const bf16* __restrict__ A_T,
    const float* __restrict__ rn, const float* __restrict__ mn,
    const float* __restrict__ vr, const float* __restrict__ wts,
    const float* __restrict__ kvm, const float* __restrict__ kvv,
    bf16* __restrict__ attnb) {
  __shared__ bf16 Qs[64 * 72];
  __shared__ bf16 Ap[64 * 72];
  __shared__ bf16 Ah[64 * 72];
  __shared__ float qrnL[64], qmnL[64], qvrL[64], kvmL[64], kvvL[64];
  int qt = blockIdx.x, hbid = blockIdx.y;
  int h = hbid >> 2, b = hbid & 3;
  int tid = threadIdx.x;
  int wv = tid >> 6, l = tid & 63, fr = l & 15, lq = l >> 4;
  {
    int row = tid >> 2, qq = (tid & 3) * 16;
    const bf16* qsrc = f_q + (size_t)(b * 1024 + qt * 64 + row) * 512 + h * 64 + qq;
    *(short8v*)&Qs[row * 72 + qq] = *(const short8v*)qsrc;
    *(short8v*)&Qs[row * 72 + qq + 8] = *(const short8v*)(qsrc + 8);
    const bf16* asrc = A_T + (size_t)hbid * 8192 + row * 64 + qq;
    *(short8v*)&Ap[row * 72 + qq] = *(const short8v*)asrc;
    *(short8v*)&Ap[row * 72 + qq + 8] = *(const short8v*)(asrc + 8);
    *(short8v*)&Ah[row * 72 + qq] = *(const short8v*)(asrc + 4096);
    *(short8v*)&Ah[row * 72 + qq + 8] = *(const short8v*)(asrc + 4096 + 8);
  }
  if (tid < 64) {
    qrnL[tid] = rn[(size_t)hbid * 1024 + qt * 64 + tid];
    qmnL[tid] = mn[(size_t)hbid * 1024 + qt * 64 + tid];
    qvrL[tid] = vr[(size_t)hbid * 1024 + qt * 64 + tid];
    kvmL[tid] = kvm[hbid * 64 + tid];
    kvvL[tid] = kvv[hbid * 64 + tid];
  }
  __syncthreads();
  f32x4 ap_[4], ah_[4];
#pragma unroll
  for (int j = 0; j < 4; ++j)
#pragma unroll
    for (int e = 0; e < 4; ++e) { ap_[j][e] = 0.f; ah_[j][e] = 0.f; }
#pragma unroll
  for (int kk = 0; kk < 64; kk += 32) {
    short8v aq = *(const short8v*)&Qs[(wv * 16 + fr) * 72 + kk + lq * 8];
#pragma unroll
    for (int j = 0; j < 4; ++j) {
      short8v bp = *(const short8v*)&Ap[(j * 16 + fr) * 72 + kk + lq * 8];
      short8v bh = *(const short8v*)&Ah[(j * 16 + fr) * 72 + kk + lq * 8];
      ap_[j] = __builtin_amdgcn_mfma_f32_16x16x32_bf16(aq, bp, ap_[j], 0, 0, 0);
      ah_[j] = __builtin_amdgcn_mfma_f32_16x16x32_bf16(aq, bh, ah_[j], 0, 0, 0);
    }
  }
  float w0 = wts[h * 3 + 0], w1 = wts[h * 3 + 1], w2 = wts[h * 3 + 2];
  float f1 = w1 * (1.f / 64.f), w264 = w2 * (1.f / 64.f);
#pragma unroll
  for (int j = 0; j < 4; ++j) {
    int dv = j * 16 + fr;
    float km = kvmL[dv], kv2 = kvvL[dv];
#pragma unroll
    for (int rr = 0; rr < 4; ++rr) {
      int n = wv * 16 + lq * 4 + rr;
      float o = w0 * qrnL[n] * ah_[j][rr] + f1 * ap_[j][rr]
              - w1 * qmnL[n] * km + w264 * qvrL[n] * kv2;
      attnb[(size_t)(b * 1024 + qt * 64 + n) * 512 + h * 64 + dv] = __float2bfloat16(o);
    }
  }
}

extern "C" void kernel_launch(void* const* d_in, const int* in_sizes, int n_in,
                              void* d_out, int out_size, void* d_ws, size_t ws_size,
                              hipStream_t stream) {
  const float* q     = (const float*)d_in[0];
  const float* k     = (const float*)d_in[1];
  const float* v     = (const float*)d_in[2];
  const float* ln_g  = (const float*)d_in[3];
  const float* ln_b  = (const float*)d_in[4];
  const float* W_in  = (const float*)d_in[5];
  const float* W_out = (const float*)d_in[6];
  const float* b_out = (const float*)d_in[7];
  const float* wp_W1 = (const float*)d_in[8];
  const float* wp_b1 = (const float*)d_in[9];
  const float* wp_lg = (const float*)d_in[10];
  const float* wp_lb = (const float*)d_in[11];
  const float* wp_W2 = (const float*)d_in[12];
  const float* wp_b2 = (const float*)d_in[13];
  float* out = (float*)d_out;

  char* w8 = (char*)d_ws;
  bf16* abf   = (bf16*)(w8);                              // 12 MB (ln'd q,k,v)
  bf16* f_q   = (bf16*)(w8 + (12u << 20));                // 4 MB
  bf16* fkt   = (bf16*)(w8 + (16u << 20));                // 4 MB
  bf16* fkh   = (bf16*)(w8 + (20u << 20));                // 4 MB
  bf16* fvt   = (bf16*)(w8 + (24u << 20));                // 4 MB
  bf16* attnb = (bf16*)(w8 + (28u << 20));                // 4 MB
  bf16* A_T   = (bf16*)(w8 + (32u << 20));                // 512 KB
  bf16* Wib   = (bf16*)(w8 + (32u << 20) + (512u << 10)); // 512 KB
  bf16* Wob   = (bf16*)(w8 + (33u << 20));                // 512 KB
  float* fb   = (float*)(w8 + (33u << 20) + (512u << 10));
  float* rn  = fb;            // 32768
  float* mn  = fb + 32768;    // 65536 (q, k)
  float* vr  = fb + 98304;    // 65536
  float* gp  = fb + 163840;   // 65536 ([2*64][512])
  float* kvm = fb + 229376;   // 2048
  float* kvv = fb + 231424;   // 2048
  float* wts = fb + 233472;   // 24

  lncvt_kernel<<<3200, 256, 0, stream>>>(q, k, v, ln_g, ln_b, W_in, W_out,
                                         abf, Wib, Wob);
  proj_kernel<<<dim3(4, 192), 256, 0, stream>>>(
      abf, Wib, f_q, fkt, fkh, fvt, rn, mn, vr, gp);
  aux_kernel<<<65, 256, 0, stream>>>(
      fvt, fkt, fkh, mn, vr, gp, wp_W1, wp_b1, wp_lg, wp_lb, wp_W2, wp_b2,
      A_T, kvm, kvv, wts);
  apply_kernel<<<dim3(16, 32), 256, 0, stream>>>(
      f_q, A_T, rn, mn, vr, wts, kvm, kvv, attnb);
  outproj_kernel<<<dim3(4, 64), 256, 0, stream>>>(attnb, Wob, b_out, out);
}

// Round 9
// 63.822 us; speedup vs baseline: 1.6436x; 1.2989x over previous
//
#include <hip/hip_runtime.h>
#include <hip/hip_bf16.h>

#define LN_EPS 1e-5f
typedef __attribute__((ext_vector_type(8))) short short8v;
typedef __attribute__((ext_vector_type(4))) short short4v;
typedef __attribute__((ext_vector_type(4))) float f32x4;
typedef __hip_bfloat16 bf16;

__device__ inline float wred_sum(float v) {
#pragma unroll
  for (int off = 1; off < 64; off <<= 1) v += __shfl_xor(v, off, 64);
  return v;
}
__device__ inline float b2f(short s) {
  return __uint_as_float(((unsigned)(unsigned short)s) << 16);
}
__device__ inline short f2bs(float x) {
  union { bf16 h; short s; } u; u.h = __float2bfloat16(x); return u.s;
}
__device__ inline float rbf(float x) {
  return __bfloat162float(__float2bfloat16(x));
}

// ---- fused: LN(q,k,v) -> bf16 rows  |  W_in/W_out f32 -> bf16 ---------------
__global__ __launch_bounds__(256) void lncvt_kernel(
    const float* __restrict__ q, const float* __restrict__ k,
    const float* __restrict__ v,
    const float* __restrict__ g, const float* __restrict__ bln,
    const float* __restrict__ Wi, const float* __restrict__ Wo,
    bf16* __restrict__ abf, bf16* __restrict__ Wib, bf16* __restrict__ Wob) {
  int bid = blockIdx.x, tid = threadIdx.x;
  if (bid < 3072) {
    int wave = tid >> 6, lane = tid & 63;
    int grow = bid * 4 + wave;                // 0..12287
    int tensor = grow >> 12, row = grow & 4095;
    const float* src = tensor == 0 ? q : (tensor == 1 ? k : v);
    const float4* p = (const float4*)(src + (size_t)row * 512 + lane * 8);
    float4 a = p[0], b = p[1];
    float s  = a.x + a.y + a.z + a.w + b.x + b.y + b.z + b.w;
    float ss = a.x*a.x + a.y*a.y + a.z*a.z + a.w*a.w
             + b.x*b.x + b.y*b.y + b.z*b.z + b.w*b.w;
    s = wred_sum(s);
    ss = wred_sum(ss);
    float m = s * (1.f / 512.f);
    float r = rsqrtf(ss * (1.f / 512.f) - m * m + LN_EPS);
    float4 g0 = *(const float4*)(g + lane * 8);
    float4 g1 = *(const float4*)(g + lane * 8 + 4);
    float4 b0 = *(const float4*)(bln + lane * 8);
    float4 b1 = *(const float4*)(bln + lane * 8 + 4);
    short8v t;
    t[0] = f2bs((a.x - m) * r * g0.x + b0.x);
    t[1] = f2bs((a.y - m) * r * g0.y + b0.y);
    t[2] = f2bs((a.z - m) * r * g0.z + b0.z);
    t[3] = f2bs((a.w - m) * r * g0.w + b0.w);
    t[4] = f2bs((b.x - m) * r * g1.x + b1.x);
    t[5] = f2bs((b.y - m) * r * g1.y + b1.y);
    t[6] = f2bs((b.z - m) * r * g1.z + b1.z);
    t[7] = f2bs((b.w - m) * r * g1.w + b1.w);
    *(short8v*)(abf + (size_t)grow * 512 + lane * 8) = t;
  } else {
    int e0 = ((bid - 3072) * 256 + tid) * 8;
    float4 a = *(const float4*)(Wi + e0);
    float4 b = *(const float4*)(Wi + e0 + 4);
    short8v t;
    t[0] = f2bs(a.x); t[1] = f2bs(a.y); t[2] = f2bs(a.z); t[3] = f2bs(a.w);
    t[4] = f2bs(b.x); t[5] = f2bs(b.y); t[6] = f2bs(b.z); t[7] = f2bs(b.w);
    *(short8v*)(Wib + e0) = t;
    a = *(const float4*)(Wo + e0);
    b = *(const float4*)(Wo + e0 + 4);
    t[0] = f2bs(a.x); t[1] = f2bs(a.y); t[2] = f2bs(a.z); t[3] = f2bs(a.w);
    t[4] = f2bs(b.x); t[5] = f2bs(b.y); t[6] = f2bs(b.z); t[7] = f2bs(b.w);
    *(short8v*)(Wob + e0) = t;
  }
}

// ---- proj: 64x128-tile GEMM abf @ Wib^T + full epilogue (R8, unchanged) -----
__global__ __launch_bounds__(256) void proj_kernel(
    const bf16* __restrict__ Asrc, const bf16* __restrict__ Wb,
    bf16* __restrict__ f_q, bf16* __restrict__ fkt, bf16* __restrict__ fkh,
    bf16* __restrict__ fvt,
    float* __restrict__ rn, float* __restrict__ mn, float* __restrict__ vr,
    float* __restrict__ gp) {
  __shared__ __attribute__((aligned(16))) bf16 As[64 * 64];
  __shared__ __attribute__((aligned(16))) bf16 Bs[128 * 64];
  __shared__ float gpbuf[4][128];
  int tid = threadIdx.x;
  int bj = blockIdx.x, bi = blockIdx.y;
  int row0 = bi * 64;
  int wv = tid >> 6, l = tid & 63, fr = l & 15, lq = l >> 4;
  f32x4 acc[8];
#pragma unroll
  for (int j = 0; j < 8; ++j)
#pragma unroll
    for (int e = 0; e < 4; ++e) acc[j][e] = 0.f;

  int swz = (fr & 7) << 4;

  for (int ks = 0; ks < 512; ks += 64) {
#pragma unroll
    for (int c = 0; c < 2; ++c) {
      int off = wv * 2048 + c * 1024 + l * 16;
      int ar = off >> 7;
      int sc = (off & 127) ^ ((ar & 7) << 4);
      const char* gsrc = (const char*)(Asrc + (size_t)(row0 + ar) * 512 + ks) + sc;
      __builtin_amdgcn_global_load_lds(gsrc, (char*)As + wv * 2048 + c * 1024, 16, 0, 0);
    }
#pragma unroll
    for (int c = 0; c < 4; ++c) {
      int off = wv * 4096 + c * 1024 + l * 16;
      int br = off >> 7;
      int sc = (off & 127) ^ ((br & 7) << 4);
      const char* gsrc = (const char*)(Wb + (size_t)(bj * 128 + br) * 512 + ks) + sc;
      __builtin_amdgcn_global_load_lds(gsrc, (char*)Bs + wv * 4096 + c * 1024, 16, 0, 0);
    }
    __syncthreads();
#pragma unroll
    for (int kk = 0; kk < 64; kk += 32) {
      int csw = (kk * 2 + lq * 16) ^ swz;
      short8v af = *(const short8v*)&As[(wv * 16 + fr) * 64 + (csw >> 1)];
#pragma unroll
      for (int j = 0; j < 8; ++j) {
        short8v bv = *(const short8v*)&Bs[(j * 16 + fr) * 64 + (csw >> 1)];
        acc[j] = __builtin_amdgcn_mfma_f32_16x16x32_bf16(af, bv, acc[j], 0, 0, 0);
      }
    }
    __syncthreads();
  }

  int tensor = bi >> 6, rb = bi & 63;
  int b = rb >> 4, n0 = (rb & 15) * 64;
  int nbase = n0 + wv * 16 + lq * 4;
  if (tensor == 2) {
#pragma unroll
    for (int j = 0; j < 8; ++j) {
      int h = bj * 2 + (j >> 2), hb = h * 4 + b;
      int dv = (j & 3) * 16 + fr;
      short4v t;
#pragma unroll
      for (int rr = 0; rr < 4; ++rr) t[rr] = f2bs(acc[j][rr]);
      *(short4v*)(fvt + (size_t)(hb * 64 + dv) * 1024 + nbase) = t;
    }
    return;
  }
  float vb[8][4];
#pragma unroll
  for (int j = 0; j < 8; ++j)
#pragma unroll
    for (int rr = 0; rr < 4; ++rr) vb[j][rr] = rbf(acc[j][rr]);

#pragma unroll
  for (int hh = 0; hh < 2; ++hh) {
    int h = bj * 2 + hh, hb = h * 4 + b;
    float sr[4], s2[4];
#pragma unroll
    for (int rr = 0; rr < 4; ++rr) {
      float s = 0.f, ss = 0.f;
#pragma unroll
      for (int jj = 0; jj < 4; ++jj) {
        float x = vb[hh * 4 + jj][rr];
        s += x; ss += x * x;
      }
#pragma unroll
      for (int off = 1; off < 16; off <<= 1) {
        s += __shfl_xor(s, off, 64);
        ss += __shfl_xor(ss, off, 64);
      }
      sr[rr] = s; s2[rr] = ss;
    }
    if (tensor == 0) {
#pragma unroll
      for (int jj = 0; jj < 4; ++jj) {
        int d = jj * 16 + fr;
#pragma unroll
        for (int rr = 0; rr < 4; ++rr)
          f_q[(size_t)(b * 1024 + nbase + rr) * 512 + h * 64 + d] =
              __float2bfloat16(acc[hh * 4 + jj][rr]);
      }
      if (fr == 0)
#pragma unroll
        for (int rr = 0; rr < 4; ++rr) {
          size_t idx = (size_t)hb * 1024 + nbase + rr;
          float mean = sr[rr] * (1.f / 64.f);
          rn[idx] = rsqrtf(s2[rr]);
          mn[idx] = mean;
          vr[idx] = (s2[rr] - 64.f * mean * mean) * (1.f / 63.f);
        }
    } else {
      float rnv[4];
#pragma unroll
      for (int rr = 0; rr < 4; ++rr) rnv[rr] = rsqrtf(s2[rr]);
#pragma unroll
      for (int jj = 0; jj < 4; ++jj) {
        int dk = jj * 16 + fr;
        short4v tp, th;
#pragma unroll
        for (int rr = 0; rr < 4; ++rr) {
          tp[rr] = f2bs(acc[hh * 4 + jj][rr]);
          th[rr] = f2bs(vb[hh * 4 + jj][rr] * rnv[rr]);
        }
        size_t off = (size_t)(hb * 64 + dk) * 1024 + nbase;
        *(short4v*)(fkt + off) = tp;
        *(short4v*)(fkh + off) = th;
      }
      if (fr == 0)
#pragma unroll
        for (int rr = 0; rr < 4; ++rr) {
          size_t idx = 32768 + (size_t)hb * 1024 + nbase + rr;
          float mean = sr[rr] * (1.f / 64.f);
          mn[idx] = mean;
          vr[idx] = (s2[rr] - 64.f * mean * mean) * (1.f / 63.f);
        }
    }
  }
#pragma unroll
  for (int j = 0; j < 8; ++j) {
    float c = 0.f;
#pragma unroll
    for (int rr = 0; rr < 4; ++rr) c += vb[j][rr];
    c += __shfl_xor(c, 16, 64);
    c += __shfl_xor(c, 32, 64);
    if (lq == 0) gpbuf[wv][j * 16 + fr] = c;
  }
  __syncthreads();
  if (tid < 128)
    gp[(size_t)(tensor * 64 + rb) * 512 + bj * 128 + tid] =
        gpbuf[0][tid] + gpbuf[1][tid] + gpbuf[2][tid] + gpbuf[3][tid];
}

// ---- outproj: 64x128-tile GEMM attnb @ Wob^T + bias -> f32 out (R8) ---------
__global__ __launch_bounds__(256) void outproj_kernel(
    const bf16* __restrict__ Ab, const bf16* __restrict__ Wb,
    const float* __restrict__ bias, float* __restrict__ out) {
  __shared__ __attribute__((aligned(16))) bf16 As[64 * 64];
  __shared__ __attribute__((aligned(16))) bf16 Bs[128 * 64];
  int tid = threadIdx.x;
  int bj = blockIdx.x, bi = blockIdx.y;
  int row0 = bi * 64;
  int wv = tid >> 6, l = tid & 63, fr = l & 15, lq = l >> 4;
  f32x4 acc[8];
#pragma unroll
  for (int j = 0; j < 8; ++j)
#pragma unroll
    for (int e = 0; e < 4; ++e) acc[j][e] = 0.f;

  int swz = (fr & 7) << 4;

  for (int ks = 0; ks < 512; ks += 64) {
#pragma unroll
    for (int c = 0; c < 2; ++c) {
      int off = wv * 2048 + c * 1024 + l * 16;
      int ar = off >> 7;
      int sc = (off & 127) ^ ((ar & 7) << 4);
      const char* gsrc = (const char*)(Ab + (size_t)(row0 + ar) * 512 + ks) + sc;
      __builtin_amdgcn_global_load_lds(gsrc, (char*)As + wv * 2048 + c * 1024, 16, 0, 0);
    }
#pragma unroll
    for (int c = 0; c < 4; ++c) {
      int off = wv * 4096 + c * 1024 + l * 16;
      int br = off >> 7;
      int sc = (off & 127) ^ ((br & 7) << 4);
      const char* gsrc = (const char*)(Wb + (size_t)(bj * 128 + br) * 512 + ks) + sc;
      __builtin_amdgcn_global_load_lds(gsrc, (char*)Bs + wv * 4096 + c * 1024, 16, 0, 0);
    }
    __syncthreads();
#pragma unroll
    for (int kk = 0; kk < 64; kk += 32) {
      int csw = (kk * 2 + lq * 16) ^ swz;
      short8v af = *(const short8v*)&As[(wv * 16 + fr) * 64 + (csw >> 1)];
#pragma unroll
      for (int j = 0; j < 8; ++j) {
        short8v bv = *(const short8v*)&Bs[(j * 16 + fr) * 64 + (csw >> 1)];
        acc[j] = __builtin_amdgcn_mfma_f32_16x16x32_bf16(af, bv, acc[j], 0, 0, 0);
      }
    }
    __syncthreads();
  }
#pragma unroll
  for (int j = 0; j < 8; ++j) {
    int col = bj * 128 + j * 16 + fr;
    float bvv = bias[col];
#pragma unroll
    for (int rr = 0; rr < 4; ++rr)
      out[(size_t)(row0 + wv * 16 + lq * 4 + rr) * 512 + col] = acc[j][rr] + bvv;
  }
}

// ---- aux: KtV partials (128) | rank1 (32) | per-head MLP (8) ----------------
__global__ __launch_bounds__(256) void aux_kernel(
    const bf16* __restrict__ fvt, const bf16* __restrict__ fkt,
    const bf16* __restrict__ fkh,
    const float* __restrict__ mn, const float* __restrict__ vr,
    const float* __restrict__ gp,
    const float* __restrict__ W1, const float* __restrict__ b1,
    const float* __restrict__ lg, const float* __restrict__ lb,
    const float* __restrict__ W2, const float* __restrict__ b2,
    float* __restrict__ part, float* __restrict__ kvm, float* __restrict__ kvv,
    float* __restrict__ wts) {
  __shared__ float sh[2560];
  int bid = blockIdx.x, tid = threadIdx.x;
  int wv = tid >> 6, l = tid & 63, fr = l & 15, lq = l >> 4;
  if (bid < 128) {
    // ---- KtV partials: K-chunk mc of 256 ----
    int hb = bid >> 2, mc = bid & 3;
    f32x4 apl[4], aht[4];
#pragma unroll
    for (int j = 0; j < 4; ++j)
#pragma unroll
      for (int e = 0; e < 4; ++e) { apl[j][e] = 0.f; aht[j][e] = 0.f; }
    size_t arow = (size_t)(hb * 64 + wv * 16 + fr) * 1024;
#pragma unroll 2
    for (int m0 = 0; m0 < 256; m0 += 32) {
      size_t moff = mc * 256 + m0 + lq * 8;
      short8v av = *(const short8v*)(fvt + arow + moff);
#pragma unroll
      for (int j = 0; j < 4; ++j) {
        size_t brow = (size_t)(hb * 64 + j * 16 + fr) * 1024 + moff;
        short8v bp = *(const short8v*)(fkt + brow);
        short8v bh = *(const short8v*)(fkh + brow);
        apl[j] = __builtin_amdgcn_mfma_f32_16x16x32_bf16(av, bp, apl[j], 0, 0, 0);
        aht[j] = __builtin_amdgcn_mfma_f32_16x16x32_bf16(av, bh, aht[j], 0, 0, 0);
      }
    }
    size_t base = (size_t)(hb * 4 + mc) * 8192;
#pragma unroll
    for (int j = 0; j < 4; ++j)
#pragma unroll
      for (int rr = 0; rr < 4; ++rr) {
        int dv = wv * 16 + lq * 4 + rr, dk = j * 16 + fr;
        part[base + dv * 64 + dk] = apl[j][rr];
        part[base + 4096 + dv * 64 + dk] = aht[j][rr];
      }
  } else if (bid < 160) {
    // ---- rank1 ----
    int hb = bid - 128;
    float* kmL = sh; float* kvL = sh + 1024; float* red = sh + 2048;
    for (int i = tid; i < 1024; i += 256) {
      kmL[i] = mn[32768 + hb * 1024 + i];
      kvL[i] = vr[32768 + hb * 1024 + i];
    }
    __syncthreads();
    int dv = tid >> 2, seg = tid & 3;
    float am = 0.f, av = 0.f;
    size_t rowb = (size_t)(hb * 64 + dv) * 1024 + seg * 256;
    for (int i = 0; i < 256; i += 8) {
      short8v vv = *(const short8v*)(fvt + rowb + i);
#pragma unroll
      for (int e = 0; e < 8; ++e) {
        float f = b2f(vv[e]);
        am += kmL[seg * 256 + i + e] * f;
        av += kvL[seg * 256 + i + e] * f;
      }
    }
    red[dv * 4 + seg] = am;
    red[256 + dv * 4 + seg] = av;
    __syncthreads();
    if (tid < 64) {
      kvm[hb * 64 + tid] = red[tid * 4] + red[tid * 4 + 1] + red[tid * 4 + 2] + red[tid * 4 + 3];
      kvv[hb * 64 + tid] = red[256 + tid * 4] + red[256 + tid * 4 + 1] +
                           red[256 + tid * 4 + 2] + red[256 + tid * 4 + 3];
    }
  } else {
    // ---- per-head MLP: bid 160..167 -> head h, 256 threads cooperate ----
    int h = bid - 160;
    float* red = sh;              // [4][128]
    float* fqv = sh + 512;        // [64]
    float* fkv = sh + 576;        // [64]
    float* pred = sh + 640;       // [4][64]
    int cl = tid & 63, part4 = tid >> 6;
    float sq = 0.f, sk = 0.f;
#pragma unroll
    for (int p = 0; p < 16; ++p) {
      sq += gp[(size_t)(part4 * 16 + p) * 512 + h * 64 + cl];
      sk += gp[(size_t)(64 + part4 * 16 + p) * 512 + h * 64 + cl];
    }
    red[part4 * 128 + cl] = sq;
    red[part4 * 128 + 64 + cl] = sk;
    __syncthreads();
    if (tid < 128) {
      float vsum = red[tid] + red[128 + tid] + red[256 + tid] + red[384 + tid];
      if (tid < 64) fqv[tid] = vsum * (1.f / 4096.f);
      else          fkv[tid - 64] = vsum * (1.f / 4096.f);
    }
    __syncthreads();
    int j = tid & 63;
    float pp = 0.f;
#pragma unroll
    for (int i = 0; i < 16; ++i) {
      pp += fqv[part4 * 16 + i] * W1[j * 128 + part4 * 16 + i];
      pp += fkv[part4 * 16 + i] * W1[j * 128 + 64 + part4 * 16 + i];
    }
    pred[part4 * 64 + j] = pp;
    __syncthreads();
    if (tid < 64) {
      float pre = b1[j] + pred[j] + pred[64 + j] + pred[128 + j] + pred[192 + j];
      float s = wred_sum(pre);
      float ss = wred_sum(pre * pre);
      float mean = s * (1.f / 64.f);
      float var = ss * (1.f / 64.f) - mean * mean;
      float hdn = (pre - mean) * rsqrtf(var + LN_EPS) * lg[j] + lb[j];
      hdn = fmaxf(hdn, 0.f);
      float l0 = wred_sum(hdn * W2[0 * 64 + j]) + b2[0];
      float l1 = wred_sum(hdn * W2[1 * 64 + j]) + b2[1];
      float l2 = wred_sum(hdn * W2[2 * 64 + j]) + b2[2];
      float mx = fmaxf(l0, fmaxf(l1, l2));
      float e0 = __expf(l0 - mx), e1 = __expf(l1 - mx), e2 = __expf(l2 - mx);
      float inv = 1.f / (e0 + e1 + e2);
      if (j == 0) {
        wts[h * 3 + 0] = e0 * inv;
        wts[h * 3 + 1] = e1 * inv;
        wts[h * 3 + 2] = e2 * inv;
      }
    }
  }
}

// ---- apply: out = w0*qrn*(Q@Ahat^T) + f1*(Q@Apl^T) + rank1 ------------------
// Stages Ap/Ah by summing the 4 KtV f32 partials inline.
__global__ __launch_bounds__(256) void apply_kernel(
    const bf16* __restrict__ f_q, const float* __restrict__ Gpart,
    const float* __restrict__ rn, const float* __restrict__ mn,
    const float* __restrict__ vr, const float* __restrict__ wts,
    const float* __restrict__ kvm, const float* __restrict__ kvv,
    bf16* __restrict__ attnb) {
  __shared__ bf16 Qs[64 * 72];
  __shared__ bf16 Ap[64 * 72];
  __shared__ bf16 Ah[64 * 72];
  __shared__ float qrnL[64], qmnL[64], qvrL[64], kvmL[64], kvvL[64];
  int qt = blockIdx.x, hbid = blockIdx.y;
  int h = hbid >> 2, b = hbid & 3;
  int tid = threadIdx.x;
  int wv = tid >> 6, l = tid & 63, fr = l & 15, lq = l >> 4;
  {
    int row = tid >> 2, qq = (tid & 3) * 16;
    const bf16* qsrc = f_q + (size_t)(b * 1024 + qt * 64 + row) * 512 + h * 64 + qq;
    *(short8v*)&Qs[row * 72 + qq] = *(const short8v*)qsrc;
    *(short8v*)&Qs[row * 72 + qq + 8] = *(const short8v*)(qsrc + 8);
    const float* psrc = Gpart + (size_t)hbid * 32768 + row * 64 + qq;
#pragma unroll
    for (int c = 0; c < 4; ++c) {
      float4 spl = {0.f, 0.f, 0.f, 0.f}, sht = {0.f, 0.f, 0.f, 0.f};
#pragma unroll
      for (int mc = 0; mc < 4; ++mc) {
        float4 p = *(const float4*)(psrc + mc * 8192 + c * 4);
        float4 t = *(const float4*)(psrc + mc * 8192 + 4096 + c * 4);
        spl.x += p.x; spl.y += p.y; spl.z += p.z; spl.w += p.w;
        sht.x += t.x; sht.y += t.y; sht.z += t.z; sht.w += t.w;
      }
      Ap[row * 72 + qq + c * 4 + 0] = __float2bfloat16(spl.x);
      Ap[row * 72 + qq + c * 4 + 1] = __float2bfloat16(spl.y);
      Ap[row * 72 + qq + c * 4 + 2] = __float2bfloat16(spl.z);
      Ap[row * 72 + qq + c * 4 + 3] = __float2bfloat16(spl.w);
      Ah[row * 72 + qq + c * 4 + 0] = __float2bfloat16(sht.x);
      Ah[row * 72 + qq + c * 4 + 1] = __float2bfloat16(sht.y);
      Ah[row * 72 + qq + c * 4 + 2] = __float2bfloat16(sht.z);
      Ah[row * 72 + qq + c * 4 + 3] = __float2bfloat16(sht.w);
    }
  }
  if (tid < 64) {
    qrnL[tid] = rn[(size_t)hbid * 1024 + qt * 64 + tid];
    qmnL[tid] = mn[(size_t)hbid * 1024 + qt * 64 + tid];
    qvrL[tid] = vr[(size_t)hbid * 1024 + qt * 64 + tid];
    kvmL[tid] = kvm[hbid * 64 + tid];
    kvvL[tid] = kvv[hbid * 64 + tid];
  }
  __syncthreads();
  f32x4 ap_[4], ah_[4];
#pragma unroll
  for (int j = 0; j < 4; ++j)
#pragma unroll
    for (int e = 0; e < 4; ++e) { ap_[j][e] = 0.f; ah_[j][e] = 0.f; }
#pragma unroll
  for (int kk = 0; kk < 64; kk += 32) {
    short8v aq = *(const short8v*)&Qs[(wv * 16 + fr) * 72 + kk + lq * 8];
#pragma unroll
    for (int j = 0; j < 4; ++j) {
      short8v bp = *(const short8v*)&Ap[(j * 16 + fr) * 72 + kk + lq * 8];
      short8v bh = *(const short8v*)&Ah[(j * 16 + fr) * 72 + kk + lq * 8];
      ap_[j] = __builtin_amdgcn_mfma_f32_16x16x32_bf16(aq, bp, ap_[j], 0, 0, 0);
      ah_[j] = __builtin_amdgcn_mfma_f32_16x16x32_bf16(aq, bh, ah_[j], 0, 0, 0);
    }
  }
  float w0 = wts[h * 3 + 0], w1 = wts[h * 3 + 1], w2 = wts[h * 3 + 2];
  float f1 = w1 * (1.f / 64.f), w264 = w2 * (1.f / 64.f);
#pragma unroll
  for (int j = 0; j < 4; ++j) {
    int dv = j * 16 + fr;
    float km = kvmL[dv], kv2 = kvvL[dv];
#pragma unroll
    for (int rr = 0; rr < 4; ++rr) {
      int n = wv * 16 + lq * 4 + rr;
      float o = w0 * qrnL[n] * ah_[j][rr] + f1 * ap_[j][rr]
              - w1 * qmnL[n] * km + w264 * qvrL[n] * kv2;
      attnb[(size_t)(b * 1024 + qt * 64 + n) * 512 + h * 64 + dv] = __float2bfloat16(o);
    }
  }
}

extern "C" void kernel_launch(void* const* d_in, const int* in_sizes, int n_in,
                              void* d_out, int out_size, void* d_ws, size_t ws_size,
                              hipStream_t stream) {
  const float* q     = (const float*)d_in[0];
  const float* k     = (const float*)d_in[1];
  const float* v     = (const float*)d_in[2];
  const float* ln_g  = (const float*)d_in[3];
  const float* ln_b  = (const float*)d_in[4];
  const float* W_in  = (const float*)d_in[5];
  const float* W_out = (const float*)d_in[6];
  const float* b_out = (const float*)d_in[7];
  const float* wp_W1 = (const float*)d_in[8];
  const float* wp_b1 = (const float*)d_in[9];
  const float* wp_lg = (const float*)d_in[10];
  const float* wp_lb = (const float*)d_in[11];
  const float* wp_W2 = (const float*)d_in[12];
  const float* wp_b2 = (const float*)d_in[13];
  float* out = (float*)d_out;

  char* w8 = (char*)d_ws;
  bf16* abf   = (bf16*)(w8);                              // 12 MB (dead after proj)
  float* Gpart = (float*)(w8);                            // 4 MB, aliases abf
  bf16* f_q   = (bf16*)(w8 + (12u << 20));                // 4 MB
  bf16* fkt   = (bf16*)(w8 + (16u << 20));                // 4 MB
  bf16* fkh   = (bf16*)(w8 + (20u << 20));                // 4 MB
  bf16* fvt   = (bf16*)(w8 + (24u << 20));                // 4 MB
  bf16* attnb = (bf16*)(w8 + (28u << 20));                // 4 MB
  bf16* Wib   = (bf16*)(w8 + (32u << 20));                // 512 KB
  bf16* Wob   = (bf16*)(w8 + (32u << 20) + (512u << 10)); // 512 KB
  float* fb   = (float*)(w8 + (33u << 20));
  float* rn  = fb;            // 32768
  float* mn  = fb + 32768;    // 65536 (q, k)
  float* vr  = fb + 98304;    // 65536
  float* gp  = fb + 163840;   // 65536 ([2*64][512])
  float* kvm = fb + 229376;   // 2048
  float* kvv = fb + 231424;   // 2048
  float* wts = fb + 233472;   // 24

  lncvt_kernel<<<3200, 256, 0, stream>>>(q, k, v, ln_g, ln_b, W_in, W_out,
                                         abf, Wib, Wob);
  proj_kernel<<<dim3(4, 192), 256, 0, stream>>>(
      abf, Wib, f_q, fkt, fkh, fvt, rn, mn, vr, gp);
  aux_kernel<<<168, 256, 0, stream>>>(
      fvt, fkt, fkh, mn, vr, gp, wp_W1, wp_b1, wp_lg, wp_lb, wp_W2, wp_b2,
      Gpart, kvm, kvv, wts);
  apply_kernel<<<dim3(16, 32), 256, 0, stream>>>(
      f_q, Gpart, rn, mn, vr, wts, kvm, kvv, attnb);
  outproj_kernel<<<dim3(4, 64), 256, 0, stream>>>(attnb, Wob, b_out, out);
}

// Round 10
// 63.783 us; speedup vs baseline: 1.6446x; 1.0006x over previous
//
#include <hip/hip_runtime.h>
#include <hip/hip_bf16.h>

#define LN_EPS 1e-5f
typedef __attribute__((ext_vector_type(8))) short short8v;
typedef __attribute__((ext_vector_type(4))) short short4v;
typedef __attribute__((ext_vector_type(4))) float f32x4;
typedef __hip_bfloat16 bf16;

__device__ inline float wred_sum(float v) {
#pragma unroll
  for (int off = 1; off < 64; off <<= 1) v += __shfl_xor(v, off, 64);
  return v;
}
__device__ inline float b2f(short s) {
  return __uint_as_float(((unsigned)(unsigned short)s) << 16);
}
__device__ inline short f2bs(float x) {
  union { bf16 h; short s; } u; u.h = __float2bfloat16(x); return u.s;
}
__device__ inline float rbf(float x) {
  return __bfloat162float(__float2bfloat16(x));
}

// ---- fused: LN(q,k,v) -> bf16 rows  |  W_in/W_out f32 -> bf16 ---------------
__global__ __launch_bounds__(256) void lncvt_kernel(
    const float* __restrict__ q, const float* __restrict__ k,
    const float* __restrict__ v,
    const float* __restrict__ g, const float* __restrict__ bln,
    const float* __restrict__ Wi, const float* __restrict__ Wo,
    bf16* __restrict__ abf, bf16* __restrict__ Wib, bf16* __restrict__ Wob) {
  int bid = blockIdx.x, tid = threadIdx.x;
  if (bid < 3072) {
    int wave = tid >> 6, lane = tid & 63;
    int grow = bid * 4 + wave;                // 0..12287
    int tensor = grow >> 12, row = grow & 4095;
    const float* src = tensor == 0 ? q : (tensor == 1 ? k : v);
    const float4* p = (const float4*)(src + (size_t)row * 512 + lane * 8);
    float4 a = p[0], b = p[1];
    float s  = a.x + a.y + a.z + a.w + b.x + b.y + b.z + b.w;
    float ss = a.x*a.x + a.y*a.y + a.z*a.z + a.w*a.w
             + b.x*b.x + b.y*b.y + b.z*b.z + b.w*b.w;
    s = wred_sum(s);
    ss = wred_sum(ss);
    float m = s * (1.f / 512.f);
    float r = rsqrtf(ss * (1.f / 512.f) - m * m + LN_EPS);
    float4 g0 = *(const float4*)(g + lane * 8);
    float4 g1 = *(const float4*)(g + lane * 8 + 4);
    float4 b0 = *(const float4*)(bln + lane * 8);
    float4 b1 = *(const float4*)(bln + lane * 8 + 4);
    short8v t;
    t[0] = f2bs((a.x - m) * r * g0.x + b0.x);
    t[1] = f2bs((a.y - m) * r * g0.y + b0.y);
    t[2] = f2bs((a.z - m) * r * g0.z + b0.z);
    t[3] = f2bs((a.w - m) * r * g0.w + b0.w);
    t[4] = f2bs((b.x - m) * r * g1.x + b1.x);
    t[5] = f2bs((b.y - m) * r * g1.y + b1.y);
    t[6] = f2bs((b.z - m) * r * g1.z + b1.z);
    t[7] = f2bs((b.w - m) * r * g1.w + b1.w);
    *(short8v*)(abf + (size_t)grow * 512 + lane * 8) = t;
  } else {
    int e0 = ((bid - 3072) * 256 + tid) * 8;
    float4 a = *(const float4*)(Wi + e0);
    float4 b = *(const float4*)(Wi + e0 + 4);
    short8v t;
    t[0] = f2bs(a.x); t[1] = f2bs(a.y); t[2] = f2bs(a.z); t[3] = f2bs(a.w);
    t[4] = f2bs(b.x); t[5] = f2bs(b.y); t[6] = f2bs(b.z); t[7] = f2bs(b.w);
    *(short8v*)(Wib + e0) = t;
    a = *(const float4*)(Wo + e0);
    b = *(const float4*)(Wo + e0 + 4);
    t[0] = f2bs(a.x); t[1] = f2bs(a.y); t[2] = f2bs(a.z); t[3] = f2bs(a.w);
    t[4] = f2bs(b.x); t[5] = f2bs(b.y); t[6] = f2bs(b.z); t[7] = f2bs(b.w);
    *(short8v*)(Wob + e0) = t;
  }
}

// ---- proj: 64x128-tile GEMM, double-buffered gload_lds, counted vmcnt -------
__global__ __launch_bounds__(256) void proj_kernel(
    const bf16* __restrict__ Asrc, const bf16* __restrict__ Wb,
    bf16* __restrict__ f_q, bf16* __restrict__ fkt, bf16* __restrict__ fkh,
    bf16* __restrict__ fvt,
    float* __restrict__ rn, float* __restrict__ mn, float* __restrict__ vr,
    float* __restrict__ gp) {
  __shared__ __attribute__((aligned(16))) bf16 As[2][64 * 64];
  __shared__ __attribute__((aligned(16))) bf16 Bs[2][128 * 64];
  __shared__ float gpbuf[4][128];
  int tid = threadIdx.x;
  int bj = blockIdx.x, bi = blockIdx.y;
  int row0 = bi * 64;
  int wv = tid >> 6, l = tid & 63, fr = l & 15, lq = l >> 4;
  f32x4 acc[8];
#pragma unroll
  for (int j = 0; j < 8; ++j)
#pragma unroll
    for (int e = 0; e < 4; ++e) acc[j][e] = 0.f;

  int swz = (fr & 7) << 4;
  // per-wave staging geometry (6 gload_lds per tile per wave)
  int offA0 = wv * 2048 + l * 16;
  int offB0 = wv * 4096 + l * 16;

#define STAGE(buf, ks)                                                        \
  {                                                                           \
    _Pragma("unroll")                                                         \
    for (int c = 0; c < 2; ++c) {                                             \
      int off = offA0 + c * 1024;                                             \
      int ar = off >> 7;                                                      \
      int sc = (off & 127) ^ ((ar & 7) << 4);                                 \
      const char* gsrc = (const char*)(Asrc + (size_t)(row0 + ar) * 512 + (ks)) + sc; \
      __builtin_amdgcn_global_load_lds(gsrc, (char*)As[buf] + wv * 2048 + c * 1024, 16, 0, 0); \
    }                                                                         \
    _Pragma("unroll")                                                         \
    for (int c = 0; c < 4; ++c) {                                             \
      int off = offB0 + c * 1024;                                             \
      int br = off >> 7;                                                      \
      int sc = (off & 127) ^ ((br & 7) << 4);                                 \
      const char* gsrc = (const char*)(Wb + (size_t)(bj * 128 + br) * 512 + (ks)) + sc; \
      __builtin_amdgcn_global_load_lds(gsrc, (char*)Bs[buf] + wv * 4096 + c * 1024, 16, 0, 0); \
    }                                                                         \
  }

  STAGE(0, 0);
#pragma unroll
  for (int t = 0; t < 8; ++t) {
    int cur = t & 1;
    if (t < 7) {
      STAGE(cur ^ 1, (t + 1) * 64);
      asm volatile("s_waitcnt vmcnt(6)" ::: "memory");
    } else {
      asm volatile("s_waitcnt vmcnt(0)" ::: "memory");
    }
    __builtin_amdgcn_s_barrier();
#pragma unroll
    for (int kk = 0; kk < 64; kk += 32) {
      int csw = (kk * 2 + lq * 16) ^ swz;
      short8v af = *(const short8v*)&As[cur][(wv * 16 + fr) * 64 + (csw >> 1)];
#pragma unroll
      for (int j = 0; j < 8; ++j) {
        short8v bv = *(const short8v*)&Bs[cur][(j * 16 + fr) * 64 + (csw >> 1)];
        acc[j] = __builtin_amdgcn_mfma_f32_16x16x32_bf16(af, bv, acc[j], 0, 0, 0);
      }
    }
    __builtin_amdgcn_s_barrier();
  }
#undef STAGE

  int tensor = bi >> 6, rb = bi & 63;
  int b = rb >> 4, n0 = (rb & 15) * 64;
  int nbase = n0 + wv * 16 + lq * 4;
  if (tensor == 2) {
#pragma unroll
    for (int j = 0; j < 8; ++j) {
      int h = bj * 2 + (j >> 2), hb = h * 4 + b;
      int dv = (j & 3) * 16 + fr;
      short4v t;
#pragma unroll
      for (int rr = 0; rr < 4; ++rr) t[rr] = f2bs(acc[j][rr]);
      *(short4v*)(fvt + (size_t)(hb * 64 + dv) * 1024 + nbase) = t;
    }
    return;
  }
  float vb[8][4];
#pragma unroll
  for (int j = 0; j < 8; ++j)
#pragma unroll
    for (int rr = 0; rr < 4; ++rr) vb[j][rr] = rbf(acc[j][rr]);

#pragma unroll
  for (int hh = 0; hh < 2; ++hh) {
    int h = bj * 2 + hh, hb = h * 4 + b;
    float sr[4], s2[4];
#pragma unroll
    for (int rr = 0; rr < 4; ++rr) {
      float s = 0.f, ss = 0.f;
#pragma unroll
      for (int jj = 0; jj < 4; ++jj) {
        float x = vb[hh * 4 + jj][rr];
        s += x; ss += x * x;
      }
#pragma unroll
      for (int off = 1; off < 16; off <<= 1) {
        s += __shfl_xor(s, off, 64);
        ss += __shfl_xor(ss, off, 64);
      }
      sr[rr] = s; s2[rr] = ss;
    }
    if (tensor == 0) {
#pragma unroll
      for (int jj = 0; jj < 4; ++jj) {
        int d = jj * 16 + fr;
#pragma unroll
        for (int rr = 0; rr < 4; ++rr)
          f_q[(size_t)(b * 1024 + nbase + rr) * 512 + h * 64 + d] =
              __float2bfloat16(acc[hh * 4 + jj][rr]);
      }
      if (fr == 0)
#pragma unroll
        for (int rr = 0; rr < 4; ++rr) {
          size_t idx = (size_t)hb * 1024 + nbase + rr;
          float mean = sr[rr] * (1.f / 64.f);
          rn[idx] = rsqrtf(s2[rr]);
          mn[idx] = mean;
          vr[idx] = (s2[rr] - 64.f * mean * mean) * (1.f / 63.f);
        }
    } else {
      float rnv[4];
#pragma unroll
      for (int rr = 0; rr < 4; ++rr) rnv[rr] = rsqrtf(s2[rr]);
#pragma unroll
      for (int jj = 0; jj < 4; ++jj) {
        int dk = jj * 16 + fr;
        short4v tp, th;
#pragma unroll
        for (int rr = 0; rr < 4; ++rr) {
          tp[rr] = f2bs(acc[hh * 4 + jj][rr]);
          th[rr] = f2bs(vb[hh * 4 + jj][rr] * rnv[rr]);
        }
        size_t off = (size_t)(hb * 64 + dk) * 1024 + nbase;
        *(short4v*)(fkt + off) = tp;
        *(short4v*)(fkh + off) = th;
      }
      if (fr == 0)
#pragma unroll
        for (int rr = 0; rr < 4; ++rr) {
          size_t idx = 32768 + (size_t)hb * 1024 + nbase + rr;
          float mean = sr[rr] * (1.f / 64.f);
          mn[idx] = mean;
          vr[idx] = (s2[rr] - 64.f * mean * mean) * (1.f / 63.f);
        }
    }
  }
#pragma unroll
  for (int j = 0; j < 8; ++j) {
    float c = 0.f;
#pragma unroll
    for (int rr = 0; rr < 4; ++rr) c += vb[j][rr];
    c += __shfl_xor(c, 16, 64);
    c += __shfl_xor(c, 32, 64);
    if (lq == 0) gpbuf[wv][j * 16 + fr] = c;
  }
  __syncthreads();
  if (tid < 128)
    gp[(size_t)(tensor * 64 + rb) * 512 + bj * 128 + tid] =
        gpbuf[0][tid] + gpbuf[1][tid] + gpbuf[2][tid] + gpbuf[3][tid];
}

// ---- outproj: 64x128-tile GEMM, double-buffered gload_lds, counted vmcnt ----
__global__ __launch_bounds__(256) void outproj_kernel(
    const bf16* __restrict__ Ab, const bf16* __restrict__ Wb,
    const float* __restrict__ bias, float* __restrict__ out) {
  __shared__ __attribute__((aligned(16))) bf16 As[2][64 * 64];
  __shared__ __attribute__((aligned(16))) bf16 Bs[2][128 * 64];
  int tid = threadIdx.x;
  int bj = blockIdx.x, bi = blockIdx.y;
  int row0 = bi * 64;
  int wv = tid >> 6, l = tid & 63, fr = l & 15, lq = l >> 4;
  f32x4 acc[8];
#pragma unroll
  for (int j = 0; j < 8; ++j)
#pragma unroll
    for (int e = 0; e < 4; ++e) acc[j][e] = 0.f;

  int swz = (fr & 7) << 4;
  int offA0 = wv * 2048 + l * 16;
  int offB0 = wv * 4096 + l * 16;

#define STAGE(buf, ks)                                                        \
  {                                                                           \
    _Pragma("unroll")                                                         \
    for (int c = 0; c < 2; ++c) {                                             \
      int off = offA0 + c * 1024;                                             \
      int ar = off >> 7;                                                      \
      int sc = (off & 127) ^ ((ar & 7) << 4);                                 \
      const char* gsrc = (const char*)(Ab + (size_t)(row0 + ar) * 512 + (ks)) + sc; \
      __builtin_amdgcn_global_load_lds(gsrc, (char*)As[buf] + wv * 2048 + c * 1024, 16, 0, 0); \
    }                                                                         \
    _Pragma("unroll")                                                         \
    for (int c = 0; c < 4; ++c) {                                             \
      int off = offB0 + c * 1024;                                             \
      int br = off >> 7;                                                      \
      int sc = (off & 127) ^ ((br & 7) << 4);                                 \
      const char* gsrc = (const char*)(Wb + (size_t)(bj * 128 + br) * 512 + (ks)) + sc; \
      __builtin_amdgcn_global_load_lds(gsrc, (char*)Bs[buf] + wv * 4096 + c * 1024, 16, 0, 0); \
    }                                                                         \
  }

  STAGE(0, 0);
#pragma unroll
  for (int t = 0; t < 8; ++t) {
    int cur = t & 1;
    if (t < 7) {
      STAGE(cur ^ 1, (t + 1) * 64);
      asm volatile("s_waitcnt vmcnt(6)" ::: "memory");
    } else {
      asm volatile("s_waitcnt vmcnt(0)" ::: "memory");
    }
    __builtin_amdgcn_s_barrier();
#pragma unroll
    for (int kk = 0; kk < 64; kk += 32) {
      int csw = (kk * 2 + lq * 16) ^ swz;
      short8v af = *(const short8v*)&As[cur][(wv * 16 + fr) * 64 + (csw >> 1)];
#pragma unroll
      for (int j = 0; j < 8; ++j) {
        short8v bv = *(const short8v*)&Bs[cur][(j * 16 + fr) * 64 + (csw >> 1)];
        acc[j] = __builtin_amdgcn_mfma_f32_16x16x32_bf16(af, bv, acc[j], 0, 0, 0);
      }
    }
    __builtin_amdgcn_s_barrier();
  }
#undef STAGE
#pragma unroll
  for (int j = 0; j < 8; ++j) {
    int col = bj * 128 + j * 16 + fr;
    float bvv = bias[col];
#pragma unroll
    for (int rr = 0; rr < 4; ++rr)
      out[(size_t)(row0 + wv * 16 + lq * 4 + rr) * 512 + col] = acc[j][rr] + bvv;
  }
}

// ---- aux: KtV partials (128) | rank1 (32) | per-head MLP (8) ----------------
__global__ __launch_bounds__(256) void aux_kernel(
    const bf16* __restrict__ fvt, const bf16* __restrict__ fkt,
    const bf16* __restrict__ fkh,
    const float* __restrict__ mn, const float* __restrict__ vr,
    const float* __restrict__ gp,
    const float* __restrict__ W1, const float* __restrict__ b1,
    const float* __restrict__ lg, const float* __restrict__ lb,
    const float* __restrict__ W2, const float* __restrict__ b2,
    float* __restrict__ part, float* __restrict__ kvm, float* __restrict__ kvv,
    float* __restrict__ wts) {
  __shared__ float sh[2560];
  int bid = blockIdx.x, tid = threadIdx.x;
  int wv = tid >> 6, l = tid & 63, fr = l & 15, lq = l >> 4;
  if (bid < 128) {
    int hb = bid >> 2, mc = bid & 3;
    f32x4 apl[4], aht[4];
#pragma unroll
    for (int j = 0; j < 4; ++j)
#pragma unroll
      for (int e = 0; e < 4; ++e) { apl[j][e] = 0.f; aht[j][e] = 0.f; }
    size_t arow = (size_t)(hb * 64 + wv * 16 + fr) * 1024;
#pragma unroll 2
    for (int m0 = 0; m0 < 256; m0 += 32) {
      size_t moff = mc * 256 + m0 + lq * 8;
      short8v av = *(const short8v*)(fvt + arow + moff);
#pragma unroll
      for (int j = 0; j < 4; ++j) {
        size_t brow = (size_t)(hb * 64 + j * 16 + fr) * 1024 + moff;
        short8v bp = *(const short8v*)(fkt + brow);
        short8v bh = *(const short8v*)(fkh + brow);
        apl[j] = __builtin_amdgcn_mfma_f32_16x16x32_bf16(av, bp, apl[j], 0, 0, 0);
        aht[j] = __builtin_amdgcn_mfma_f32_16x16x32_bf16(av, bh, aht[j], 0, 0, 0);
      }
    }
    size_t base = (size_t)(hb * 4 + mc) * 8192;
#pragma unroll
    for (int j = 0; j < 4; ++j)
#pragma unroll
      for (int rr = 0; rr < 4; ++rr) {
        int dv = wv * 16 + lq * 4 + rr, dk = j * 16 + fr;
        part[base + dv * 64 + dk] = apl[j][rr];
        part[base + 4096 + dv * 64 + dk] = aht[j][rr];
      }
  } else if (bid < 160) {
    int hb = bid - 128;
    float* kmL = sh; float* kvL = sh + 1024; float* red = sh + 2048;
    for (int i = tid; i < 1024; i += 256) {
      kmL[i] = mn[32768 + hb * 1024 + i];
      kvL[i] = vr[32768 + hb * 1024 + i];
    }
    __syncthreads();
    int dv = tid >> 2, seg = tid & 3;
    float am = 0.f, av = 0.f;
    size_t rowb = (size_t)(hb * 64 + dv) * 1024 + seg * 256;
    for (int i = 0; i < 256; i += 8) {
      short8v vv = *(const short8v*)(fvt + rowb + i);
#pragma unroll
      for (int e = 0; e < 8; ++e) {
        float f = b2f(vv[e]);
        am += kmL[seg * 256 + i + e] * f;
        av += kvL[seg * 256 + i + e] * f;
      }
    }
    red[dv * 4 + seg] = am;
    red[256 + dv * 4 + seg] = av;
    __syncthreads();
    if (tid < 64) {
      kvm[hb * 64 + tid] = red[tid * 4] + red[tid * 4 + 1] + red[tid * 4 + 2] + red[tid * 4 + 3];
      kvv[hb * 64 + tid] = red[256 + tid * 4] + red[256 + tid * 4 + 1] +
                           red[256 + tid * 4 + 2] + red[256 + tid * 4 + 3];
    }
  } else {
    int h = bid - 160;
    float* red = sh;
    float* fqv = sh + 512;
    float* fkv = sh + 576;
    float* pred = sh + 640;
    int cl = tid & 63, part4 = tid >> 6;
    float sq = 0.f, sk = 0.f;
#pragma unroll
    for (int p = 0; p < 16; ++p) {
      sq += gp[(size_t)(part4 * 16 + p) * 512 + h * 64 + cl];
      sk += gp[(size_t)(64 + part4 * 16 + p) * 512 + h * 64 + cl];
    }
    red[part4 * 128 + cl] = sq;
    red[part4 * 128 + 64 + cl] = sk;
    __syncthreads();
    if (tid < 128) {
      float vsum = red[tid] + red[128 + tid] + red[256 + tid] + red[384 + tid];
      if (tid < 64) fqv[tid] = vsum * (1.f / 4096.f);
      else          fkv[tid - 64] = vsum * (1.f / 4096.f);
    }
    __syncthreads();
    int j = tid & 63;
    float pp = 0.f;
#pragma unroll
    for (int i = 0; i < 16; ++i) {
      pp += fqv[part4 * 16 + i] * W1[j * 128 + part4 * 16 + i];
      pp += fkv[part4 * 16 + i] * W1[j * 128 + 64 + part4 * 16 + i];
    }
    pred[part4 * 64 + j] = pp;
    __syncthreads();
    if (tid < 64) {
      float pre = b1[j] + pred[j] + pred[64 + j] + pred[128 + j] + pred[192 + j];
      float s = wred_sum(pre);
      float ss = wred_sum(pre * pre);
      float mean = s * (1.f / 64.f);
      float var = ss * (1.f / 64.f) - mean * mean;
      float hdn = (pre - mean) * rsqrtf(var + LN_EPS) * lg[j] + lb[j];
      hdn = fmaxf(hdn, 0.f);
      float l0 = wred_sum(hdn * W2[0 * 64 + j]) + b2[0];
      float l1 = wred_sum(hdn * W2[1 * 64 + j]) + b2[1];
      float l2 = wred_sum(hdn * W2[2 * 64 + j]) + b2[2];
      float mx = fmaxf(l0, fmaxf(l1, l2));
      float e0 = __expf(l0 - mx), e1 = __expf(l1 - mx), e2 = __expf(l2 - mx);
      float inv = 1.f / (e0 + e1 + e2);
      if (j == 0) {
        wts[h * 3 + 0] = e0 * inv;
        wts[h * 3 + 1] = e1 * inv;
        wts[h * 3 + 2] = e2 * inv;
      }
    }
  }
}

// ---- apply: out = w0*qrn*(Q@Ahat^T) + f1*(Q@Apl^T) + rank1 ------------------
__global__ __launch_bounds__(256) void apply_kernel(
    const bf16* __restrict__ f_q, const float* __restrict__ Gpart,
    const float* __restrict__ rn, const float* __restrict__ mn,
    const float* __restrict__ vr, const float* __restrict__ wts,
    const float* __restrict__ kvm, const float* __restrict__ kvv,
    bf16* __restrict__ attnb) {
  __shared__ bf16 Qs[64 * 72];
  __shared__ bf16 Ap[64 * 72];
  __shared__ bf16 Ah[64 * 72];
  __shared__ float qrnL[64], qmnL[64], qvrL[64], kvmL[64], kvvL[64];
  int qt = blockIdx.x, hbid = blockIdx.y;
  int h = hbid >> 2, b = hbid & 3;
  int tid = threadIdx.x;
  int wv = tid >> 6, l = tid & 63, fr = l & 15, lq = l >> 4;
  {
    int row = tid >> 2, qq = (tid & 3) * 16;
    const bf16* qsrc = f_q + (size_t)(b * 1024 + qt * 64 + row) * 512 + h * 64 + qq;
    *(short8v*)&Qs[row * 72 + qq] = *(const short8v*)qsrc;
    *(short8v*)&Qs[row * 72 + qq + 8] = *(const short8v*)(qsrc + 8);
    const float* psrc = Gpart + (size_t)hbid * 32768 + row * 64 + qq;
#pragma unroll
    for (int c = 0; c < 4; ++c) {
      float4 spl = {0.f, 0.f, 0.f, 0.f}, sht = {0.f, 0.f, 0.f, 0.f};
#pragma unroll
      for (int mc = 0; mc < 4; ++mc) {
        float4 p = *(const float4*)(psrc + mc * 8192 + c * 4);
        float4 t = *(const float4*)(psrc + mc * 8192 + 4096 + c * 4);
        spl.x += p.x; spl.y += p.y; spl.z += p.z; spl.w += p.w;
        sht.x += t.x; sht.y += t.y; sht.z += t.z; sht.w += t.w;
      }
      Ap[row * 72 + qq + c * 4 + 0] = __float2bfloat16(spl.x);
      Ap[row * 72 + qq + c * 4 + 1] = __float2bfloat16(spl.y);
      Ap[row * 72 + qq + c * 4 + 2] = __float2bfloat16(spl.z);
      Ap[row * 72 + qq + c * 4 + 3] = __float2bfloat16(spl.w);
      Ah[row * 72 + qq + c * 4 + 0] = __float2bfloat16(sht.x);
      Ah[row * 72 + qq + c * 4 + 1] = __float2bfloat16(sht.y);
      Ah[row * 72 + qq + c * 4 + 2] = __float2bfloat16(sht.z);
      Ah[row * 72 + qq + c * 4 + 3] = __float2bfloat16(sht.w);
    }
  }
  if (tid < 64) {
    qrnL[tid] = rn[(size_t)hbid * 1024 + qt * 64 + tid];
    qmnL[tid] = mn[(size_t)hbid * 1024 + qt * 64 + tid];
    qvrL[tid] = vr[(size_t)hbid * 1024 + qt * 64 + tid];
    kvmL[tid] = kvm[hbid * 64 + tid];
    kvvL[tid] = kvv[hbid * 64 + tid];
  }
  __syncthreads();
  f32x4 ap_[4], ah_[4];
#pragma unroll
  for (int j = 0; j < 4; ++j)
#pragma unroll
    for (int e = 0; e < 4; ++e) { ap_[j][e] = 0.f; ah_[j][e] = 0.f; }
#pragma unroll
  for (int kk = 0; kk < 64; kk += 32) {
    short8v aq = *(const short8v*)&Qs[(wv * 16 + fr) * 72 + kk + lq * 8];
#pragma unroll
    for (int j = 0; j < 4; ++j) {
      short8v bp = *(const short8v*)&Ap[(j * 16 + fr) * 72 + kk + lq * 8];
      short8v bh = *(const short8v*)&Ah[(j * 16 + fr) * 72 + kk + lq * 8];
      ap_[j] = __builtin_amdgcn_mfma_f32_16x16x32_bf16(aq, bp, ap_[j], 0, 0, 0);
      ah_[j] = __builtin_amdgcn_mfma_f32_16x16x32_bf16(aq, bh, ah_[j], 0, 0, 0);
    }
  }
  float w0 = wts[h * 3 + 0], w1 = wts[h * 3 + 1], w2 = wts[h * 3 + 2];
  float f1 = w1 * (1.f / 64.f), w264 = w2 * (1.f / 64.f);
#pragma unroll
  for (int j = 0; j < 4; ++j) {
    int dv = j * 16 + fr;
    float km = kvmL[dv], kv2 = kvvL[dv];
#pragma unroll
    for (int rr = 0; rr < 4; ++rr) {
      int n = wv * 16 + lq * 4 + rr;
      float o = w0 * qrnL[n] * ah_[j][rr] + f1 * ap_[j][rr]
              - w1 * qmnL[n] * km + w264 * qvrL[n] * kv2;
      attnb[(size_t)(b * 1024 + qt * 64 + n) * 512 + h * 64 + dv] = __float2bfloat16(o);
    }
  }
}

extern "C" void kernel_launch(void* const* d_in, const int* in_sizes, int n_in,
                              void* d_out, int out_size, void* d_ws, size_t ws_size,
                              hipStream_t stream) {
  const float* q     = (const float*)d_in[0];
  const float* k     = (const float*)d_in[1];
  const float* v     = (const float*)d_in[2];
  const float* ln_g  = (const float*)d_in[3];
  const float* ln_b  = (const float*)d_in[4];
  const float* W_in  = (const float*)d_in[5];
  const float* W_out = (const float*)d_in[6];
  const float* b_out = (const float*)d_in[7];
  const float* wp_W1 = (const float*)d_in[8];
  const float* wp_b1 = (const float*)d_in[9];
  const float* wp_lg = (const float*)d_in[10];
  const float* wp_lb = (const float*)d_in[11];
  const float* wp_W2 = (const float*)d_in[12];
  const float* wp_b2 = (const float*)d_in[13];
  float* out = (float*)d_out;

  char* w8 = (char*)d_ws;
  bf16* abf   = (bf16*)(w8);                              // 12 MB (dead after proj)
  float* Gpart = (float*)(w8);                            // 4 MB, aliases abf
  bf16* f_q   = (bf16*)(w8 + (12u << 20));                // 4 MB
  bf16* fkt   = (bf16*)(w8 + (16u << 20));                // 4 MB
  bf16* fkh   = (bf16*)(w8 + (20u << 20));                // 4 MB
  bf16* fvt   = (bf16*)(w8 + (24u << 20));                // 4 MB
  bf16* attnb = (bf16*)(w8 + (28u << 20));                // 4 MB
  bf16* Wib   = (bf16*)(w8 + (32u << 20));                // 512 KB
  bf16* Wob   = (bf16*)(w8 + (32u << 20) + (512u << 10)); // 512 KB
  float* fb   = (float*)(w8 + (33u << 20));
  float* rn  = fb;            // 32768
  float* mn  = fb + 32768;    // 65536 (q, k)
  float* vr  = fb + 98304;    // 65536
  float* gp  = fb + 163840;   // 65536 ([2*64][512])
  float* kvm = fb + 229376;   // 2048
  float* kvv = fb + 231424;   // 2048
  float* wts = fb + 233472;   // 24

  lncvt_kernel<<<3200, 256, 0, stream>>>(q, k, v, ln_g, ln_b, W_in, W_out,
                                         abf, Wib, Wob);
  proj_kernel<<<dim3(4, 192), 256, 0, stream>>>(
      abf, Wib, f_q, fkt, fkh, fvt, rn, mn, vr, gp);
  aux_kernel<<<168, 256, 0, stream>>>(
      fvt, fkt, fkh, mn, vr, gp, wp_W1, wp_b1, wp_lg, wp_lb, wp_W2, wp_b2,
      Gpart, kvm, kvv, wts);
  apply_kernel<<<dim3(16, 32), 256, 0, stream>>>(
      f_q, Gpart, rn, mn, vr, wts, kvm, kvv, attnb);
  outproj_kernel<<<dim3(4, 64), 256, 0, stream>>>(attnb, Wob, b_out, out);
}

// Round 11
// 62.529 us; speedup vs baseline: 1.6776x; 1.0201x over previous
//
#include <hip/hip_runtime.h>
#include <hip/hip_bf16.h>

#define LN_EPS 1e-5f
typedef __attribute__((ext_vector_type(8))) short short8v;
typedef __attribute__((ext_vector_type(4))) short short4v;
typedef __attribute__((ext_vector_type(4))) float f32x4;
typedef __hip_bfloat16 bf16;

__device__ inline float wred_sum(float v) {
#pragma unroll
  for (int off = 1; off < 64; off <<= 1) v += __shfl_xor(v, off, 64);
  return v;
}
__device__ inline float b2f(short s) {
  return __uint_as_float(((unsigned)(unsigned short)s) << 16);
}
__device__ inline short f2bs(float x) {
  union { bf16 h; short s; } u; u.h = __float2bfloat16(x); return u.s;
}
__device__ inline float rbf(float x) {
  return __bfloat162float(__float2bfloat16(x));
}

// ---- fused: LN(q,k,v) -> bf16 rows  |  W_in/W_out f32 -> bf16 ---------------
__global__ __launch_bounds__(256) void lncvt_kernel(
    const float* __restrict__ q, const float* __restrict__ k,
    const float* __restrict__ v,
    const float* __restrict__ g, const float* __restrict__ bln,
    const float* __restrict__ Wi, const float* __restrict__ Wo,
    bf16* __restrict__ abf, bf16* __restrict__ Wib, bf16* __restrict__ Wob) {
  int bid = blockIdx.x, tid = threadIdx.x;
  if (bid < 3072) {
    int wave = tid >> 6, lane = tid & 63;
    int grow = bid * 4 + wave;                // 0..12287
    int tensor = grow >> 12, row = grow & 4095;
    const float* src = tensor == 0 ? q : (tensor == 1 ? k : v);
    const float4* p = (const float4*)(src + (size_t)row * 512 + lane * 8);
    float4 a = p[0], b = p[1];
    float s  = a.x + a.y + a.z + a.w + b.x + b.y + b.z + b.w;
    float ss = a.x*a.x + a.y*a.y + a.z*a.z + a.w*a.w
             + b.x*b.x + b.y*b.y + b.z*b.z + b.w*b.w;
    s = wred_sum(s);
    ss = wred_sum(ss);
    float m = s * (1.f / 512.f);
    float r = rsqrtf(ss * (1.f / 512.f) - m * m + LN_EPS);
    float4 g0 = *(const float4*)(g + lane * 8);
    float4 g1 = *(const float4*)(g + lane * 8 + 4);
    float4 b0 = *(const float4*)(bln + lane * 8);
    float4 b1 = *(const float4*)(bln + lane * 8 + 4);
    short8v t;
    t[0] = f2bs((a.x - m) * r * g0.x + b0.x);
    t[1] = f2bs((a.y - m) * r * g0.y + b0.y);
    t[2] = f2bs((a.z - m) * r * g0.z + b0.z);
    t[3] = f2bs((a.w - m) * r * g0.w + b0.w);
    t[4] = f2bs((b.x - m) * r * g1.x + b1.x);
    t[5] = f2bs((b.y - m) * r * g1.y + b1.y);
    t[6] = f2bs((b.z - m) * r * g1.z + b1.z);
    t[7] = f2bs((b.w - m) * r * g1.w + b1.w);
    *(short8v*)(abf + (size_t)grow * 512 + lane * 8) = t;
  } else {
    int e0 = ((bid - 3072) * 256 + tid) * 8;
    float4 a = *(const float4*)(Wi + e0);
    float4 b = *(const float4*)(Wi + e0 + 4);
    short8v t;
    t[0] = f2bs(a.x); t[1] = f2bs(a.y); t[2] = f2bs(a.z); t[3] = f2bs(a.w);
    t[4] = f2bs(b.x); t[5] = f2bs(b.y); t[6] = f2bs(b.z); t[7] = f2bs(b.w);
    *(short8v*)(Wib + e0) = t;
    a = *(const float4*)(Wo + e0);
    b = *(const float4*)(Wo + e0 + 4);
    t[0] = f2bs(a.x); t[1] = f2bs(a.y); t[2] = f2bs(a.z); t[3] = f2bs(a.w);
    t[4] = f2bs(b.x); t[5] = f2bs(b.y); t[6] = f2bs(b.z); t[7] = f2bs(b.w);
    *(short8v*)(Wob + e0) = t;
  }
}

// ---- proj: 64x128 tile, 2x2 waves of 32x64 (6 LDS reads / 8 MFMA) -----------
__global__ __launch_bounds__(256) void proj_kernel(
    const bf16* __restrict__ Asrc, const bf16* __restrict__ Wb,
    bf16* __restrict__ f_q, bf16* __restrict__ fkt, bf16* __restrict__ fkh,
    bf16* __restrict__ fvt,
    float* __restrict__ rn, float* __restrict__ mn, float* __restrict__ vr,
    float* __restrict__ gp) {
  __shared__ __attribute__((aligned(16))) bf16 As[2][64 * 64];
  __shared__ __attribute__((aligned(16))) bf16 Bs[2][128 * 64];
  __shared__ float gpbuf[2][128];
  int tid = threadIdx.x;
  int bj = blockIdx.x, bi = blockIdx.y;
  int row0 = bi * 64;
  int wv = tid >> 6, l = tid & 63, fr = l & 15, lq = l >> 4;
  int wr = wv >> 1, wc = wv & 1;
  f32x4 acc[2][4];
#pragma unroll
  for (int a = 0; a < 2; ++a)
#pragma unroll
    for (int j = 0; j < 4; ++j)
#pragma unroll
      for (int e = 0; e < 4; ++e) acc[a][j][e] = 0.f;

  int swz = (fr & 7) << 4;
  int offA0 = wv * 2048 + l * 16;
  int offB0 = wv * 4096 + l * 16;

#define STAGE(buf, ks)                                                        \
  {                                                                           \
    _Pragma("unroll")                                                         \
    for (int c = 0; c < 2; ++c) {                                             \
      int off = offA0 + c * 1024;                                             \
      int ar = off >> 7;                                                      \
      int sc = (off & 127) ^ ((ar & 7) << 4);                                 \
      const char* gsrc = (const char*)(Asrc + (size_t)(row0 + ar) * 512 + (ks)) + sc; \
      __builtin_amdgcn_global_load_lds(gsrc, (char*)As[buf] + wv * 2048 + c * 1024, 16, 0, 0); \
    }                                                                         \
    _Pragma("unroll")                                                         \
    for (int c = 0; c < 4; ++c) {                                             \
      int off = offB0 + c * 1024;                                             \
      int br = off >> 7;                                                      \
      int sc = (off & 127) ^ ((br & 7) << 4);                                 \
      const char* gsrc = (const char*)(Wb + (size_t)(bj * 128 + br) * 512 + (ks)) + sc; \
      __builtin_amdgcn_global_load_lds(gsrc, (char*)Bs[buf] + wv * 4096 + c * 1024, 16, 0, 0); \
    }                                                                         \
  }

  STAGE(0, 0);
#pragma unroll
  for (int t = 0; t < 8; ++t) {
    int cur = t & 1;
    if (t < 7) {
      STAGE(cur ^ 1, (t + 1) * 64);
      asm volatile("s_waitcnt vmcnt(6)" ::: "memory");
    } else {
      asm volatile("s_waitcnt vmcnt(0)" ::: "memory");
    }
    __builtin_amdgcn_s_barrier();
#pragma unroll
    for (int kk = 0; kk < 64; kk += 32) {
      int csw = (kk * 2 + lq * 16) ^ swz;
      short8v a0 = *(const short8v*)&As[cur][(wr * 32 + fr) * 64 + (csw >> 1)];
      short8v a1 = *(const short8v*)&As[cur][(wr * 32 + 16 + fr) * 64 + (csw >> 1)];
#pragma unroll
      for (int j = 0; j < 4; ++j) {
        short8v bv = *(const short8v*)&Bs[cur][(wc * 64 + j * 16 + fr) * 64 + (csw >> 1)];
        acc[0][j] = __builtin_amdgcn_mfma_f32_16x16x32_bf16(a0, bv, acc[0][j], 0, 0, 0);
        acc[1][j] = __builtin_amdgcn_mfma_f32_16x16x32_bf16(a1, bv, acc[1][j], 0, 0, 0);
      }
    }
    __builtin_amdgcn_s_barrier();
  }
#undef STAGE

  int tensor = bi >> 6, rb = bi & 63;
  int b = rb >> 4, n0 = (rb & 15) * 64;
  int h = bj * 2 + wc, hb = h * 4 + b;
  if (tensor == 2) {
#pragma unroll
    for (int a = 0; a < 2; ++a) {
      int m0l = n0 + wr * 32 + a * 16 + lq * 4;
#pragma unroll
      for (int j = 0; j < 4; ++j) {
        int dv = j * 16 + fr;
        short4v t;
#pragma unroll
        for (int rr = 0; rr < 4; ++rr) t[rr] = f2bs(acc[a][j][rr]);
        *(short4v*)(fvt + (size_t)(hb * 64 + dv) * 1024 + m0l) = t;
      }
    }
    return;
  }
  float vb[2][4][4];
#pragma unroll
  for (int a = 0; a < 2; ++a)
#pragma unroll
    for (int j = 0; j < 4; ++j)
#pragma unroll
      for (int rr = 0; rr < 4; ++rr) vb[a][j][rr] = rbf(acc[a][j][rr]);

#pragma unroll
  for (int a = 0; a < 2; ++a) {
    float sr[4], s2[4];
#pragma unroll
    for (int rr = 0; rr < 4; ++rr) {
      float s = 0.f, ss = 0.f;
#pragma unroll
      for (int j = 0; j < 4; ++j) {
        float x = vb[a][j][rr];
        s += x; ss += x * x;
      }
#pragma unroll
      for (int off = 1; off < 16; off <<= 1) {
        s += __shfl_xor(s, off, 64);
        ss += __shfl_xor(ss, off, 64);
      }
      sr[rr] = s; s2[rr] = ss;
    }
    int nbase = n0 + wr * 32 + a * 16 + lq * 4;
    if (tensor == 0) {
#pragma unroll
      for (int j = 0; j < 4; ++j) {
        int d = j * 16 + fr;
#pragma unroll
        for (int rr = 0; rr < 4; ++rr)
          f_q[(size_t)(b * 1024 + nbase + rr) * 512 + h * 64 + d] =
              __float2bfloat16(acc[a][j][rr]);
      }
      if (fr == 0)
#pragma unroll
        for (int rr = 0; rr < 4; ++rr) {
          size_t idx = (size_t)hb * 1024 + nbase + rr;
          float mean = sr[rr] * (1.f / 64.f);
          rn[idx] = rsqrtf(s2[rr]);
          mn[idx] = mean;
          vr[idx] = (s2[rr] - 64.f * mean * mean) * (1.f / 63.f);
        }
    } else {
      float rnv[4];
#pragma unroll
      for (int rr = 0; rr < 4; ++rr) rnv[rr] = rsqrtf(s2[rr]);
#pragma unroll
      for (int j = 0; j < 4; ++j) {
        int dk = j * 16 + fr;
        short4v tp, th;
#pragma unroll
        for (int rr = 0; rr < 4; ++rr) {
          tp[rr] = f2bs(acc[a][j][rr]);
          th[rr] = f2bs(vb[a][j][rr] * rnv[rr]);
        }
        size_t off = (size_t)(hb * 64 + dk) * 1024 + nbase;
        *(short4v*)(fkt + off) = tp;
        *(short4v*)(fkh + off) = th;
      }
      if (fr == 0)
#pragma unroll
        for (int rr = 0; rr < 4; ++rr) {
          size_t idx = 32768 + (size_t)hb * 1024 + nbase + rr;
          float mean = sr[rr] * (1.f / 64.f);
          mn[idx] = mean;
          vr[idx] = (s2[rr] - 64.f * mean * mean) * (1.f / 63.f);
        }
    }
  }
  // global-mean column partials: wave (wr,wc) covers cols wc*64 + j*16 + fr
#pragma unroll
  for (int j = 0; j < 4; ++j) {
    float c = 0.f;
#pragma unroll
    for (int a = 0; a < 2; ++a)
#pragma unroll
      for (int rr = 0; rr < 4; ++rr) c += vb[a][j][rr];
    c += __shfl_xor(c, 16, 64);
    c += __shfl_xor(c, 32, 64);
    if (lq == 0) gpbuf[wr][wc * 64 + j * 16 + fr] = c;
  }
  __syncthreads();
  if (tid < 128)
    gp[(size_t)(tensor * 64 + rb) * 512 + bj * 128 + tid] =
        gpbuf[0][tid] + gpbuf[1][tid];
}

// ---- outproj: 64x128 tile, 2x2 waves of 32x64 -------------------------------
__global__ __launch_bounds__(256) void outproj_kernel(
    const bf16* __restrict__ Ab, const bf16* __restrict__ Wb,
    const float* __restrict__ bias, float* __restrict__ out) {
  __shared__ __attribute__((aligned(16))) bf16 As[2][64 * 64];
  __shared__ __attribute__((aligned(16))) bf16 Bs[2][128 * 64];
  int tid = threadIdx.x;
  int bj = blockIdx.x, bi = blockIdx.y;
  int row0 = bi * 64;
  int wv = tid >> 6, l = tid & 63, fr = l & 15, lq = l >> 4;
  int wr = wv >> 1, wc = wv & 1;
  f32x4 acc[2][4];
#pragma unroll
  for (int a = 0; a < 2; ++a)
#pragma unroll
    for (int j = 0; j < 4; ++j)
#pragma unroll
      for (int e = 0; e < 4; ++e) acc[a][j][e] = 0.f;

  int swz = (fr & 7) << 4;
  int offA0 = wv * 2048 + l * 16;
  int offB0 = wv * 4096 + l * 16;

#define STAGE(buf, ks)                                                        \
  {                                                                           \
    _Pragma("unroll")                                                         \
    for (int c = 0; c < 2; ++c) {                                             \
      int off = offA0 + c * 1024;                                             \
      int ar = off >> 7;                                                      \
      int sc = (off & 127) ^ ((ar & 7) << 4);                                 \
      const char* gsrc = (const char*)(Ab + (size_t)(row0 + ar) * 512 + (ks)) + sc; \
      __builtin_amdgcn_global_load_lds(gsrc, (char*)As[buf] + wv * 2048 + c * 1024, 16, 0, 0); \
    }                                                                         \
    _Pragma("unroll")                                                         \
    for (int c = 0; c < 4; ++c) {                                             \
      int off = offB0 + c * 1024;                                             \
      int br = off >> 7;                                                      \
      int sc = (off & 127) ^ ((br & 7) << 4);                                 \
      const char* gsrc = (const char*)(Wb + (size_t)(bj * 128 + br) * 512 + (ks)) + sc; \
      __builtin_amdgcn_global_load_lds(gsrc, (char*)Bs[buf] + wv * 4096 + c * 1024, 16, 0, 0); \
    }                                                                         \
  }

  STAGE(0, 0);
#pragma unroll
  for (int t = 0; t < 8; ++t) {
    int cur = t & 1;
    if (t < 7) {
      STAGE(cur ^ 1, (t + 1) * 64);
      asm volatile("s_waitcnt vmcnt(6)" ::: "memory");
    } else {
      asm volatile("s_waitcnt vmcnt(0)" ::: "memory");
    }
    __builtin_amdgcn_s_barrier();
#pragma unroll
    for (int kk = 0; kk < 64; kk += 32) {
      int csw = (kk * 2 + lq * 16) ^ swz;
      short8v a0 = *(const short8v*)&As[cur][(wr * 32 + fr) * 64 + (csw >> 1)];
      short8v a1 = *(const short8v*)&As[cur][(wr * 32 + 16 + fr) * 64 + (csw >> 1)];
#pragma unroll
      for (int j = 0; j < 4; ++j) {
        short8v bv = *(const short8v*)&Bs[cur][(wc * 64 + j * 16 + fr) * 64 + (csw >> 1)];
        acc[0][j] = __builtin_amdgcn_mfma_f32_16x16x32_bf16(a0, bv, acc[0][j], 0, 0, 0);
        acc[1][j] = __builtin_amdgcn_mfma_f32_16x16x32_bf16(a1, bv, acc[1][j], 0, 0, 0);
      }
    }
    __builtin_amdgcn_s_barrier();
  }
#undef STAGE
#pragma unroll
  for (int a = 0; a < 2; ++a)
#pragma unroll
    for (int j = 0; j < 4; ++j) {
      int col = bj * 128 + wc * 64 + j * 16 + fr;
      float bvv = bias[col];
#pragma unroll
      for (int rr = 0; rr < 4; ++rr)
        out[(size_t)(row0 + wr * 32 + a * 16 + lq * 4 + rr) * 512 + col] =
            acc[a][j][rr] + bvv;
    }
}

// ---- aux: KtV partials (128) | rank1 (32) | per-head MLP (8) ----------------
__global__ __launch_bounds__(256) void aux_kernel(
    const bf16* __restrict__ fvt, const bf16* __restrict__ fkt,
    const bf16* __restrict__ fkh,
    const float* __restrict__ mn, const float* __restrict__ vr,
    const float* __restrict__ gp,
    const float* __restrict__ W1, const float* __restrict__ b1,
    const float* __restrict__ lg, const float* __restrict__ lb,
    const float* __restrict__ W2, const float* __restrict__ b2,
    float* __restrict__ part, float* __restrict__ kvm, float* __restrict__ kvv,
    float* __restrict__ wts) {
  __shared__ float sh[2560];
  int bid = blockIdx.x, tid = threadIdx.x;
  int wv = tid >> 6, l = tid & 63, fr = l & 15, lq = l >> 4;
  if (bid < 128) {
    int hb = bid >> 2, mc = bid & 3;
    f32x4 apl[4], aht[4];
#pragma unroll
    for (int j = 0; j < 4; ++j)
#pragma unroll
      for (int e = 0; e < 4; ++e) { apl[j][e] = 0.f; aht[j][e] = 0.f; }
    size_t arow = (size_t)(hb * 64 + wv * 16 + fr) * 1024;
#pragma unroll 2
    for (int m0 = 0; m0 < 256; m0 += 32) {
      size_t moff = mc * 256 + m0 + lq * 8;
      short8v av = *(const short8v*)(fvt + arow + moff);
#pragma unroll
      for (int j = 0; j < 4; ++j) {
        size_t brow = (size_t)(hb * 64 + j * 16 + fr) * 1024 + moff;
        short8v bp = *(const short8v*)(fkt + brow);
        short8v bh = *(const short8v*)(fkh + brow);
        apl[j] = __builtin_amdgcn_mfma_f32_16x16x32_bf16(av, bp, apl[j], 0, 0, 0);
        aht[j] = __builtin_amdgcn_mfma_f32_16x16x32_bf16(av, bh, aht[j], 0, 0, 0);
      }
    }
    size_t base = (size_t)(hb * 4 + mc) * 8192;
#pragma unroll
    for (int j = 0; j < 4; ++j)
#pragma unroll
      for (int rr = 0; rr < 4; ++rr) {
        int dv = wv * 16 + lq * 4 + rr, dk = j * 16 + fr;
        part[base + dv * 64 + dk] = apl[j][rr];
        part[base + 4096 + dv * 64 + dk] = aht[j][rr];
      }
  } else if (bid < 160) {
    int hb = bid - 128;
    float* kmL = sh; float* kvL = sh + 1024; float* red = sh + 2048;
    for (int i = tid; i < 1024; i += 256) {
      kmL[i] = mn[32768 + hb * 1024 + i];
      kvL[i] = vr[32768 + hb * 1024 + i];
    }
    __syncthreads();
    int dv = tid >> 2, seg = tid & 3;
    float am = 0.f, av = 0.f;
    size_t rowb = (size_t)(hb * 64 + dv) * 1024 + seg * 256;
    for (int i = 0; i < 256; i += 8) {
      short8v vv = *(const short8v*)(fvt + rowb + i);
#pragma unroll
      for (int e = 0; e < 8; ++e) {
        float f = b2f(vv[e]);
        am += kmL[seg * 256 + i + e] * f;
        av += kvL[seg * 256 + i + e] * f;
      }
    }
    red[dv * 4 + seg] = am;
    red[256 + dv * 4 + seg] = av;
    __syncthreads();
    if (tid < 64) {
      kvm[hb * 64 + tid] = red[tid * 4] + red[tid * 4 + 1] + red[tid * 4 + 2] + red[tid * 4 + 3];
      kvv[hb * 64 + tid] = red[256 + tid * 4] + red[256 + tid * 4 + 1] +
                           red[256 + tid * 4 + 2] + red[256 + tid * 4 + 3];
    }
  } else {
    int h = bid - 160;
    float* red = sh;
    float* fqv = sh + 512;
    float* fkv = sh + 576;
    float* pred = sh + 640;
    int cl = tid & 63, part4 = tid >> 6;
    float sq = 0.f, sk = 0.f;
#pragma unroll
    for (int p = 0; p < 16; ++p) {
      sq += gp[(size_t)(part4 * 16 + p) * 512 + h * 64 + cl];
      sk += gp[(size_t)(64 + part4 * 16 + p) * 512 + h * 64 + cl];
    }
    red[part4 * 128 + cl] = sq;
    red[part4 * 128 + 64 + cl] = sk;
    __syncthreads();
    if (tid < 128) {
      float vsum = red[tid] + red[128 + tid] + red[256 + tid] + red[384 + tid];
      if (tid < 64) fqv[tid] = vsum * (1.f / 4096.f);
      else          fkv[tid - 64] = vsum * (1.f / 4096.f);
    }
    __syncthreads();
    int j = tid & 63;
    float pp = 0.f;
#pragma unroll
    for (int i = 0; i < 16; ++i) {
      pp += fqv[part4 * 16 + i] * W1[j * 128 + part4 * 16 + i];
      pp += fkv[part4 * 16 + i] * W1[j * 128 + 64 + part4 * 16 + i];
    }
    pred[part4 * 64 + j] = pp;
    __syncthreads();
    if (tid < 64) {
      float pre = b1[j] + pred[j] + pred[64 + j] + pred[128 + j] + pred[192 + j];
      float s = wred_sum(pre);
      float ss = wred_sum(pre * pre);
      float mean = s * (1.f / 64.f);
      float var = ss * (1.f / 64.f) - mean * mean;
      float hdn = (pre - mean) * rsqrtf(var + LN_EPS) * lg[j] + lb[j];
      hdn = fmaxf(hdn, 0.f);
      float l0 = wred_sum(hdn * W2[0 * 64 + j]) + b2[0];
      float l1 = wred_sum(hdn * W2[1 * 64 + j]) + b2[1];
      float l2 = wred_sum(hdn * W2[2 * 64 + j]) + b2[2];
      float mx = fmaxf(l0, fmaxf(l1, l2));
      float e0 = __expf(l0 - mx), e1 = __expf(l1 - mx), e2 = __expf(l2 - mx);
      float inv = 1.f / (e0 + e1 + e2);
      if (j == 0) {
        wts[h * 3 + 0] = e0 * inv;
        wts[h * 3 + 1] = e1 * inv;
        wts[h * 3 + 2] = e2 * inv;
      }
    }
  }
}

// ---- apply: out = w0*qrn*(Q@Ahat^T) + f1*(Q@Apl^T) + rank1 ------------------
__global__ __launch_bounds__(256) void apply_kernel(
    const bf16* __restrict__ f_q, const float* __restrict__ Gpart,
    const float* __restrict__ rn, const float* __restrict__ mn,
    const float* __restrict__ vr, const float* __restrict__ wts,
    const float* __restrict__ kvm, const float* __restrict__ kvv,
    bf16* __restrict__ attnb) {
  __shared__ bf16 Qs[64 * 72];
  __shared__ bf16 Ap[64 * 72];
  __shared__ bf16 Ah[64 * 72];
  __shared__ float qrnL[64], qmnL[64], qvrL[64], kvmL[64], kvvL[64];
  int qt = blockIdx.x, hbid = blockIdx.y;
  int h = hbid >> 2, b = hbid & 3;
  int tid = threadIdx.x;
  int wv = tid >> 6, l = tid & 63, fr = l & 15, lq = l >> 4;
  {
    int row = tid >> 2, qq = (tid & 3) * 16;
    const bf16* qsrc = f_q + (size_t)(b * 1024 + qt * 64 + row) * 512 + h * 64 + qq;
    *(short8v*)&Qs[row * 72 + qq] = *(const short8v*)qsrc;
    *(short8v*)&Qs[row * 72 + qq + 8] = *(const short8v*)(qsrc + 8);
    const float* psrc = Gpart + (size_t)hbid * 32768 + row * 64 + qq;
#pragma unroll
    for (int c = 0; c < 4; ++c) {
      float4 spl = {0.f, 0.f, 0.f, 0.f}, sht = {0.f, 0.f, 0.f, 0.f};
#pragma unroll
      for (int mc = 0; mc < 4; ++mc) {
        float4 p = *(const float4*)(psrc + mc * 8192 + c * 4);
        float4 t = *(const float4*)(psrc + mc * 8192 + 4096 + c * 4);
        spl.x += p.x; spl.y += p.y; spl.z += p.z; spl.w += p.w;
        sht.x += t.x; sht.y += t.y; sht.z += t.z; sht.w += t.w;
      }
      Ap[row * 72 + qq + c * 4 + 0] = __float2bfloat16(spl.x);
      Ap[row * 72 + qq + c * 4 + 1] = __float2bfloat16(spl.y);
      Ap[row * 72 + qq + c * 4 + 2] = __float2bfloat16(spl.z);
      Ap[row * 72 + qq + c * 4 + 3] = __float2bfloat16(spl.w);
      Ah[row * 72 + qq + c * 4 + 0] = __float2bfloat16(sht.x);
      Ah[row * 72 + qq + c * 4 + 1] = __float2bfloat16(sht.y);
      Ah[row * 72 + qq + c * 4 + 2] = __float2bfloat16(sht.z);
      Ah[row * 72 + qq + c * 4 + 3] = __float2bfloat16(sht.w);
    }
  }
  if (tid < 64) {
    qrnL[tid] = rn[(size_t)hbid * 1024 + qt * 64 + tid];
    qmnL[tid] = mn[(size_t)hbid * 1024 + qt * 64 + tid];
    qvrL[tid] = vr[(size_t)hbid * 1024 + qt * 64 + tid];
    kvmL[tid] = kvm[hbid * 64 + tid];
    kvvL[tid] = kvv[hbid * 64 + tid];
  }
  __syncthreads();
  f32x4 ap_[4], ah_[4];
#pragma unroll
  for (int j = 0; j < 4; ++j)
#pragma unroll
    for (int e = 0; e < 4; ++e) { ap_[j][e] = 0.f; ah_[j][e] = 0.f; }
#pragma unroll
  for (int kk = 0; kk < 64; kk += 32) {
    short8v aq = *(const short8v*)&Qs[(wv * 16 + fr) * 72 + kk + lq * 8];
#pragma unroll
    for (int j = 0; j < 4; ++j) {
      short8v bp = *(const short8v*)&Ap[(j * 16 + fr) * 72 + kk + lq * 8];
      short8v bh = *(const short8v*)&Ah[(j * 16 + fr) * 72 + kk + lq * 8];
      ap_[j] = __builtin_amdgcn_mfma_f32_16x16x32_bf16(aq, bp, ap_[j], 0, 0, 0);
      ah_[j] = __builtin_amdgcn_mfma_f32_16x16x32_bf16(aq, bh, ah_[j], 0, 0, 0);
    }
  }
  float w0 = wts[h * 3 + 0], w1 = wts[h * 3 + 1], w2 = wts[h * 3 + 2];
  float f1 = w1 * (1.f / 64.f), w264 = w2 * (1.f / 64.f);
#pragma unroll
  for (int j = 0; j < 4; ++j) {
    int dv = j * 16 + fr;
    float km = kvmL[dv], kv2 = kvvL[dv];
#pragma unroll
    for (int rr = 0; rr < 4; ++rr) {
      int n = wv * 16 + lq * 4 + rr;
      float o = w0 * qrnL[n] * ah_[j][rr] + f1 * ap_[j][rr]
              - w1 * qmnL[n] * km + w264 * qvrL[n] * kv2;
      attnb[(size_t)(b * 1024 + qt * 64 + n) * 512 + h * 64 + dv] = __float2bfloat16(o);
    }
  }
}

extern "C" void kernel_launch(void* const* d_in, const int* in_sizes, int n_in,
                              void* d_out, int out_size, void* d_ws, size_t ws_size,
                              hipStream_t stream) {
  const float* q     = (const float*)d_in[0];
  const float* k     = (const float*)d_in[1];
  const float* v     = (const float*)d_in[2];
  const float* ln_g  = (const float*)d_in[3];
  const float* ln_b  = (const float*)d_in[4];
  const float* W_in  = (const float*)d_in[5];
  const float* W_out = (const float*)d_in[6];
  const float* b_out = (const float*)d_in[7];
  const float* wp_W1 = (const float*)d_in[8];
  const float* wp_b1 = (const float*)d_in[9];
  const float* wp_lg = (const float*)d_in[10];
  const float* wp_lb = (const float*)d_in[11];
  const float* wp_W2 = (const float*)d_in[12];
  const float* wp_b2 = (const float*)d_in[13];
  float* out = (float*)d_out;

  char* w8 = (char*)d_ws;
  bf16* abf   = (bf16*)(w8);                              // 12 MB (dead after proj)
  float* Gpart = (float*)(w8);                            // 4 MB, aliases abf
  bf16* f_q   = (bf16*)(w8 + (12u << 20));                // 4 MB
  bf16* fkt   = (bf16*)(w8 + (16u << 20));                // 4 MB
  bf16* fkh   = (bf16*)(w8 + (20u << 20));                // 4 MB
  bf16* fvt   = (bf16*)(w8 + (24u << 20));                // 4 MB
  bf16* attnb = (bf16*)(w8 + (28u << 20));                // 4 MB
  bf16* Wib   = (bf16*)(w8 + (32u << 20));                // 512 KB
  bf16* Wob   = (bf16*)(w8 + (32u << 20) + (512u << 10)); // 512 KB
  float* fb   = (float*)(w8 + (33u << 20));
  float* rn  = fb;            // 32768
  float* mn  = fb + 32768;    // 65536 (q, k)
  float* vr  = fb + 98304;    // 65536
  float* gp  = fb + 163840;   // 65536 ([2*64][512])
  float* kvm = fb + 229376;   // 2048
  float* kvv = fb + 231424;   // 2048
  float* wts = fb + 233472;   // 24

  lncvt_kernel<<<3200, 256, 0, stream>>>(q, k, v, ln_g, ln_b, W_in, W_out,
                                         abf, Wib, Wob);
  proj_kernel<<<dim3(4, 192), 256, 0, stream>>>(
      abf, Wib, f_q, fkt, fkh, fvt, rn, mn, vr, gp);
  aux_kernel<<<168, 256, 0, stream>>>(
      fvt, fkt, fkh, mn, vr, gp, wp_W1, wp_b1, wp_lg, wp_lb, wp_W2, wp_b2,
      Gpart, kvm, kvv, wts);
  apply_kernel<<<dim3(16, 32), 256, 0, stream>>>(
      f_q, Gpart, rn, mn, vr, wts, kvm, kvv, attnb);
  outproj_kernel<<<dim3(4, 64), 256, 0, stream>>>(attnb, Wob, b_out, out);
}

// Round 12
// 59.532 us; speedup vs baseline: 1.7620x; 1.0503x over previous
//
#include <hip/hip_runtime.h>
#include <hip/hip_bf16.h>

#define LN_EPS 1e-5f
typedef __attribute__((ext_vector_type(8))) short short8v;
typedef __attribute__((ext_vector_type(4))) short short4v;
typedef __attribute__((ext_vector_type(4))) float f32x4;
typedef __hip_bfloat16 bf16;

__device__ inline float wred_sum(float v) {
#pragma unroll
  for (int off = 1; off < 64; off <<= 1) v += __shfl_xor(v, off, 64);
  return v;
}
__device__ inline float b2f(short s) {
  return __uint_as_float(((unsigned)(unsigned short)s) << 16);
}
__device__ inline short f2bs(float x) {
  union { bf16 h; short s; } u; u.h = __float2bfloat16(x); return u.s;
}
__device__ inline float rbf(float x) {
  return __bfloat162float(__float2bfloat16(x));
}

// ---- fused: LN(q,k,v) -> bf16 rows  |  W_in/W_out f32 -> bf16 ---------------
__global__ __launch_bounds__(256) void lncvt_kernel(
    const float* __restrict__ q, const float* __restrict__ k,
    const float* __restrict__ v,
    const float* __restrict__ g, const float* __restrict__ bln,
    const float* __restrict__ Wi, const float* __restrict__ Wo,
    bf16* __restrict__ abf, bf16* __restrict__ Wib, bf16* __restrict__ Wob) {
  int bid = blockIdx.x, tid = threadIdx.x;
  if (bid < 3072) {
    int wave = tid >> 6, lane = tid & 63;
    int grow = bid * 4 + wave;                // 0..12287
    int tensor = grow >> 12, row = grow & 4095;
    const float* src = tensor == 0 ? q : (tensor == 1 ? k : v);
    const float4* p = (const float4*)(src + (size_t)row * 512 + lane * 8);
    float4 a = p[0], b = p[1];
    float s  = a.x + a.y + a.z + a.w + b.x + b.y + b.z + b.w;
    float ss = a.x*a.x + a.y*a.y + a.z*a.z + a.w*a.w
             + b.x*b.x + b.y*b.y + b.z*b.z + b.w*b.w;
    s = wred_sum(s);
    ss = wred_sum(ss);
    float m = s * (1.f / 512.f);
    float r = rsqrtf(ss * (1.f / 512.f) - m * m + LN_EPS);
    float4 g0 = *(const float4*)(g + lane * 8);
    float4 g1 = *(const float4*)(g + lane * 8 + 4);
    float4 b0 = *(const float4*)(bln + lane * 8);
    float4 b1 = *(const float4*)(bln + lane * 8 + 4);
    short8v t;
    t[0] = f2bs((a.x - m) * r * g0.x + b0.x);
    t[1] = f2bs((a.y - m) * r * g0.y + b0.y);
    t[2] = f2bs((a.z - m) * r * g0.z + b0.z);
    t[3] = f2bs((a.w - m) * r * g0.w + b0.w);
    t[4] = f2bs((b.x - m) * r * g1.x + b1.x);
    t[5] = f2bs((b.y - m) * r * g1.y + b1.y);
    t[6] = f2bs((b.z - m) * r * g1.z + b1.z);
    t[7] = f2bs((b.w - m) * r * g1.w + b1.w);
    *(short8v*)(abf + (size_t)grow * 512 + lane * 8) = t;
  } else {
    int e0 = ((bid - 3072) * 256 + tid) * 8;
    float4 a = *(const float4*)(Wi + e0);
    float4 b = *(const float4*)(Wi + e0 + 4);
    short8v t;
    t[0] = f2bs(a.x); t[1] = f2bs(a.y); t[2] = f2bs(a.z); t[3] = f2bs(a.w);
    t[4] = f2bs(b.x); t[5] = f2bs(b.y); t[6] = f2bs(b.z); t[7] = f2bs(b.w);
    *(short8v*)(Wib + e0) = t;
    a = *(const float4*)(Wo + e0);
    b = *(const float4*)(Wo + e0 + 4);
    t[0] = f2bs(a.x); t[1] = f2bs(a.y); t[2] = f2bs(a.z); t[3] = f2bs(a.w);
    t[4] = f2bs(b.x); t[5] = f2bs(b.y); t[6] = f2bs(b.z); t[7] = f2bs(b.w);
    *(short8v*)(Wob + e0) = t;
  }
}

// ---- proj: 64x128 tile, 2x2 waves of 32x64, XCD-chunked swizzle -------------
__global__ __launch_bounds__(256) void proj_kernel(
    const bf16* __restrict__ Asrc, const bf16* __restrict__ Wb,
    bf16* __restrict__ f_q, bf16* __restrict__ fkt,
    bf16* __restrict__ fvt,
    float* __restrict__ rn, float* __restrict__ mn, float* __restrict__ vr,
    float* __restrict__ gp) {
  __shared__ __attribute__((aligned(16))) bf16 As[2][64 * 64];
  __shared__ __attribute__((aligned(16))) bf16 Bs[2][128 * 64];
  __shared__ float gpbuf[2][128];
  int tid = threadIdx.x;
  // XCD-chunk swizzle: 768 = 8 XCDs x 96; siblings (same bi) stay on one XCD.
  int lin = (blockIdx.x & 7) * 96 + (blockIdx.x >> 3);
  int bi = lin >> 2, bj = lin & 3;
  int row0 = bi * 64;
  int wv = tid >> 6, l = tid & 63, fr = l & 15, lq = l >> 4;
  int wr = wv >> 1, wc = wv & 1;
  f32x4 acc[2][4];
#pragma unroll
  for (int a = 0; a < 2; ++a)
#pragma unroll
    for (int j = 0; j < 4; ++j)
#pragma unroll
      for (int e = 0; e < 4; ++e) acc[a][j][e] = 0.f;

  int swz = (fr & 7) << 4;
  int offA0 = wv * 2048 + l * 16;
  int offB0 = wv * 4096 + l * 16;

#define STAGE(buf, ks)                                                        \
  {                                                                           \
    _Pragma("unroll")                                                         \
    for (int c = 0; c < 2; ++c) {                                             \
      int off = offA0 + c * 1024;                                             \
      int ar = off >> 7;                                                      \
      int sc = (off & 127) ^ ((ar & 7) << 4);                                 \
      const char* gsrc = (const char*)(Asrc + (size_t)(row0 + ar) * 512 + (ks)) + sc; \
      __builtin_amdgcn_global_load_lds(gsrc, (char*)As[buf] + wv * 2048 + c * 1024, 16, 0, 0); \
    }                                                                         \
    _Pragma("unroll")                                                         \
    for (int c = 0; c < 4; ++c) {                                             \
      int off = offB0 + c * 1024;                                             \
      int br = off >> 7;                                                      \
      int sc = (off & 127) ^ ((br & 7) << 4);                                 \
      const char* gsrc = (const char*)(Wb + (size_t)(bj * 128 + br) * 512 + (ks)) + sc; \
      __builtin_amdgcn_global_load_lds(gsrc, (char*)Bs[buf] + wv * 4096 + c * 1024, 16, 0, 0); \
    }                                                                         \
  }

  STAGE(0, 0);
#pragma unroll
  for (int t = 0; t < 8; ++t) {
    int cur = t & 1;
    if (t < 7) {
      STAGE(cur ^ 1, (t + 1) * 64);
      asm volatile("s_waitcnt vmcnt(6)" ::: "memory");
    } else {
      asm volatile("s_waitcnt vmcnt(0)" ::: "memory");
    }
    __builtin_amdgcn_s_barrier();
#pragma unroll
    for (int kk = 0; kk < 64; kk += 32) {
      int csw = (kk * 2 + lq * 16) ^ swz;
      short8v a0 = *(const short8v*)&As[cur][(wr * 32 + fr) * 64 + (csw >> 1)];
      short8v a1 = *(const short8v*)&As[cur][(wr * 32 + 16 + fr) * 64 + (csw >> 1)];
#pragma unroll
      for (int j = 0; j < 4; ++j) {
        short8v bv = *(const short8v*)&Bs[cur][(wc * 64 + j * 16 + fr) * 64 + (csw >> 1)];
        acc[0][j] = __builtin_amdgcn_mfma_f32_16x16x32_bf16(a0, bv, acc[0][j], 0, 0, 0);
        acc[1][j] = __builtin_amdgcn_mfma_f32_16x16x32_bf16(a1, bv, acc[1][j], 0, 0, 0);
      }
    }
    __builtin_amdgcn_s_barrier();
  }
#undef STAGE

  int tensor = bi >> 6, rb = bi & 63;
  int b = rb >> 4, n0 = (rb & 15) * 64;
  int h = bj * 2 + wc, hb = h * 4 + b;
  if (tensor == 2) {
#pragma unroll
    for (int a = 0; a < 2; ++a) {
      int m0l = n0 + wr * 32 + a * 16 + lq * 4;
#pragma unroll
      for (int j = 0; j < 4; ++j) {
        int dv = j * 16 + fr;
        short4v t;
#pragma unroll
        for (int rr = 0; rr < 4; ++rr) t[rr] = f2bs(acc[a][j][rr]);
        *(short4v*)(fvt + (size_t)(hb * 64 + dv) * 1024 + m0l) = t;
      }
    }
    return;
  }
  float vb[2][4][4];
#pragma unroll
  for (int a = 0; a < 2; ++a)
#pragma unroll
    for (int j = 0; j < 4; ++j)
#pragma unroll
      for (int rr = 0; rr < 4; ++rr) vb[a][j][rr] = rbf(acc[a][j][rr]);

#pragma unroll
  for (int a = 0; a < 2; ++a) {
    float sr[4], s2[4];
#pragma unroll
    for (int rr = 0; rr < 4; ++rr) {
      float s = 0.f, ss = 0.f;
#pragma unroll
      for (int j = 0; j < 4; ++j) {
        float x = vb[a][j][rr];
        s += x; ss += x * x;
      }
#pragma unroll
      for (int off = 1; off < 16; off <<= 1) {
        s += __shfl_xor(s, off, 64);
        ss += __shfl_xor(ss, off, 64);
      }
      sr[rr] = s; s2[rr] = ss;
    }
    int nbase = n0 + wr * 32 + a * 16 + lq * 4;
    if (tensor == 0) {
#pragma unroll
      for (int j = 0; j < 4; ++j) {
        int d = j * 16 + fr;
#pragma unroll
        for (int rr = 0; rr < 4; ++rr)
          f_q[(size_t)(b * 1024 + nbase + rr) * 512 + h * 64 + d] =
              __float2bfloat16(acc[a][j][rr]);
      }
      if (fr == 0)
#pragma unroll
        for (int rr = 0; rr < 4; ++rr) {
          size_t idx = (size_t)hb * 1024 + nbase + rr;
          float mean = sr[rr] * (1.f / 64.f);
          rn[idx] = rsqrtf(s2[rr]);
          mn[idx] = mean;
          vr[idx] = (s2[rr] - 64.f * mean * mean) * (1.f / 63.f);
        }
    } else {
#pragma unroll
      for (int j = 0; j < 4; ++j) {
        int dk = j * 16 + fr;
        short4v tp;
#pragma unroll
        for (int rr = 0; rr < 4; ++rr) tp[rr] = f2bs(acc[a][j][rr]);
        *(short4v*)(fkt + (size_t)(hb * 64 + dk) * 1024 + nbase) = tp;
      }
      if (fr == 0)
#pragma unroll
        for (int rr = 0; rr < 4; ++rr) {
          size_t idx = 32768 + (size_t)hb * 1024 + nbase + rr;
          float mean = sr[rr] * (1.f / 64.f);
          mn[idx] = mean;
          vr[idx] = (s2[rr] - 64.f * mean * mean) * (1.f / 63.f);
        }
    }
  }
#pragma unroll
  for (int j = 0; j < 4; ++j) {
    float c = 0.f;
#pragma unroll
    for (int a = 0; a < 2; ++a)
#pragma unroll
      for (int rr = 0; rr < 4; ++rr) c += vb[a][j][rr];
    c += __shfl_xor(c, 16, 64);
    c += __shfl_xor(c, 32, 64);
    if (lq == 0) gpbuf[wr][wc * 64 + j * 16 + fr] = c;
  }
  __syncthreads();
  if (tid < 128)
    gp[(size_t)(tensor * 64 + rb) * 512 + bj * 128 + tid] =
        gpbuf[0][tid] + gpbuf[1][tid];
}

// ---- outproj: 64x128 tile, 2x2 waves of 32x64, XCD-chunked swizzle ----------
__global__ __launch_bounds__(256) void outproj_kernel(
    const bf16* __restrict__ Ab, const bf16* __restrict__ Wb,
    const float* __restrict__ bias, float* __restrict__ out) {
  __shared__ __attribute__((aligned(16))) bf16 As[2][64 * 64];
  __shared__ __attribute__((aligned(16))) bf16 Bs[2][128 * 64];
  int tid = threadIdx.x;
  // 256 = 8 x 32
  int lin = (blockIdx.x & 7) * 32 + (blockIdx.x >> 3);
  int bi = lin >> 2, bj = lin & 3;
  int row0 = bi * 64;
  int wv = tid >> 6, l = tid & 63, fr = l & 15, lq = l >> 4;
  int wr = wv >> 1, wc = wv & 1;
  f32x4 acc[2][4];
#pragma unroll
  for (int a = 0; a < 2; ++a)
#pragma unroll
    for (int j = 0; j < 4; ++j)
#pragma unroll
      for (int e = 0; e < 4; ++e) acc[a][j][e] = 0.f;

  int swz = (fr & 7) << 4;
  int offA0 = wv * 2048 + l * 16;
  int offB0 = wv * 4096 + l * 16;

#define STAGE(buf, ks)                                                        \
  {                                                                           \
    _Pragma("unroll")                                                         \
    for (int c = 0; c < 2; ++c) {                                             \
      int off = offA0 + c * 1024;                                             \
      int ar = off >> 7;                                                      \
      int sc = (off & 127) ^ ((ar & 7) << 4);                                 \
      const char* gsrc = (const char*)(Ab + (size_t)(row0 + ar) * 512 + (ks)) + sc; \
      __builtin_amdgcn_global_load_lds(gsrc, (char*)As[buf] + wv * 2048 + c * 1024, 16, 0, 0); \
    }                                                                         \
    _Pragma("unroll")                                                         \
    for (int c = 0; c < 4; ++c) {                                             \
      int off = offB0 + c * 1024;                                             \
      int br = off >> 7;                                                      \
      int sc = (off & 127) ^ ((br & 7) << 4);                                 \
      const char* gsrc = (const char*)(Wb + (size_t)(bj * 128 + br) * 512 + (ks)) + sc; \
      __builtin_amdgcn_global_load_lds(gsrc, (char*)Bs[buf] + wv * 4096 + c * 1024, 16, 0, 0); \
    }                                                                         \
  }

  STAGE(0, 0);
#pragma unroll
  for (int t = 0; t < 8; ++t) {
    int cur = t & 1;
    if (t < 7) {
      STAGE(cur ^ 1, (t + 1) * 64);
      asm volatile("s_waitcnt vmcnt(6)" ::: "memory");
    } else {
      asm volatile("s_waitcnt vmcnt(0)" ::: "memory");
    }
    __builtin_amdgcn_s_barrier();
#pragma unroll
    for (int kk = 0; kk < 64; kk += 32) {
      int csw = (kk * 2 + lq * 16) ^ swz;
      short8v a0 = *(const short8v*)&As[cur][(wr * 32 + fr) * 64 + (csw >> 1)];
      short8v a1 = *(const short8v*)&As[cur][(wr * 32 + 16 + fr) * 64 + (csw >> 1)];
#pragma unroll
      for (int j = 0; j < 4; ++j) {
        short8v bv = *(const short8v*)&Bs[cur][(wc * 64 + j * 16 + fr) * 64 + (csw >> 1)];
        acc[0][j] = __builtin_amdgcn_mfma_f32_16x16x32_bf16(a0, bv, acc[0][j], 0, 0, 0);
        acc[1][j] = __builtin_amdgcn_mfma_f32_16x16x32_bf16(a1, bv, acc[1][j], 0, 0, 0);
      }
    }
    __builtin_amdgcn_s_barrier();
  }
#undef STAGE
#pragma unroll
  for (int a = 0; a < 2; ++a)
#pragma unroll
    for (int j = 0; j < 4; ++j) {
      int col = bj * 128 + wc * 64 + j * 16 + fr;
      float bvv = bias[col];
#pragma unroll
      for (int rr = 0; rr < 4; ++rr)
        out[(size_t)(row0 + wr * 32 + a * 16 + lq * 4 + rr) * 512 + col] =
            acc[a][j][rr] + bvv;
    }
}

// ---- aux: KtV partials (128, khat built in-register) | rank1 | MLP ----------
__global__ __launch_bounds__(256) void aux_kernel(
    const bf16* __restrict__ fvt, const bf16* __restrict__ fkt,
    const float* __restrict__ mn, const float* __restrict__ vr,
    const float* __restrict__ gp,
    const float* __restrict__ W1, const float* __restrict__ b1,
    const float* __restrict__ lg, const float* __restrict__ lb,
    const float* __restrict__ W2, const float* __restrict__ b2,
    float* __restrict__ part, float* __restrict__ kvm, float* __restrict__ kvv,
    float* __restrict__ wts) {
  __shared__ float sh[2560];
  int bid = blockIdx.x, tid = threadIdx.x;
  int wv = tid >> 6, l = tid & 63, fr = l & 15, lq = l >> 4;
  if (bid < 128) {
    int hb = bid >> 2, mc = bid & 3;
    f32x4 apl[4], aht[4];
#pragma unroll
    for (int j = 0; j < 4; ++j)
#pragma unroll
      for (int e = 0; e < 4; ++e) { apl[j][e] = 0.f; aht[j][e] = 0.f; }
    size_t arow = (size_t)(hb * 64 + wv * 16 + fr) * 1024;
#pragma unroll 2
    for (int m0 = 0; m0 < 256; m0 += 32) {
      size_t moff = mc * 256 + m0 + lq * 8;
      // reconstruct khat scale: rnv[m] = rsqrt(ss) with ss = 63*vr + 64*mn^2
      const float* mnp = mn + 32768 + (size_t)hb * 1024 + moff;
      const float* vrp = vr + 32768 + (size_t)hb * 1024 + moff;
      float4 mv0 = *(const float4*)mnp;
      float4 mv1 = *(const float4*)(mnp + 4);
      float4 vv0 = *(const float4*)vrp;
      float4 vv1 = *(const float4*)(vrp + 4);
      float rnv[8];
      rnv[0] = rsqrtf(63.f * vv0.x + 64.f * mv0.x * mv0.x);
      rnv[1] = rsqrtf(63.f * vv0.y + 64.f * mv0.y * mv0.y);
      rnv[2] = rsqrtf(63.f * vv0.z + 64.f * mv0.z * mv0.z);
      rnv[3] = rsqrtf(63.f * vv0.w + 64.f * mv0.w * mv0.w);
      rnv[4] = rsqrtf(63.f * vv1.x + 64.f * mv1.x * mv1.x);
      rnv[5] = rsqrtf(63.f * vv1.y + 64.f * mv1.y * mv1.y);
      rnv[6] = rsqrtf(63.f * vv1.z + 64.f * mv1.z * mv1.z);
      rnv[7] = rsqrtf(63.f * vv1.w + 64.f * mv1.w * mv1.w);
      short8v av = *(const short8v*)(fvt + arow + moff);
#pragma unroll
      for (int j = 0; j < 4; ++j) {
        size_t brow = (size_t)(hb * 64 + j * 16 + fr) * 1024 + moff;
        short8v bp = *(const short8v*)(fkt + brow);
        short8v bh;
#pragma unroll
        for (int e = 0; e < 8; ++e) bh[e] = f2bs(b2f(bp[e]) * rnv[e]);
        apl[j] = __builtin_amdgcn_mfma_f32_16x16x32_bf16(av, bp, apl[j], 0, 0, 0);
        aht[j] = __builtin_amdgcn_mfma_f32_16x16x32_bf16(av, bh, aht[j], 0, 0, 0);
      }
    }
    size_t base = (size_t)(hb * 4 + mc) * 8192;
#pragma unroll
    for (int j = 0; j < 4; ++j)
#pragma unroll
      for (int rr = 0; rr < 4; ++rr) {
        int dv = wv * 16 + lq * 4 + rr, dk = j * 16 + fr;
        part[base + dv * 64 + dk] = apl[j][rr];
        part[base + 4096 + dv * 64 + dk] = aht[j][rr];
      }
  } else if (bid < 160) {
    int hb = bid - 128;
    float* kmL = sh; float* kvL = sh + 1024; float* red = sh + 2048;
    for (int i = tid; i < 1024; i += 256) {
      kmL[i] = mn[32768 + hb * 1024 + i];
      kvL[i] = vr[32768 + hb * 1024 + i];
    }
    __syncthreads();
    int dv = tid >> 2, seg = tid & 3;
    float am = 0.f, av = 0.f;
    size_t rowb = (size_t)(hb * 64 + dv) * 1024 + seg * 256;
    for (int i = 0; i < 256; i += 8) {
      short8v vv = *(const short8v*)(fvt + rowb + i);
#pragma unroll
      for (int e = 0; e < 8; ++e) {
        float f = b2f(vv[e]);
        am += kmL[seg * 256 + i + e] * f;
        av += kvL[seg * 256 + i + e] * f;
      }
    }
    red[dv * 4 + seg] = am;
    red[256 + dv * 4 + seg] = av;
    __syncthreads();
    if (tid < 64) {
      kvm[hb * 64 + tid] = red[tid * 4] + red[tid * 4 + 1] + red[tid * 4 + 2] + red[tid * 4 + 3];
      kvv[hb * 64 + tid] = red[256 + tid * 4] + red[256 + tid * 4 + 1] +
                           red[256 + tid * 4 + 2] + red[256 + tid * 4 + 3];
    }
  } else {
    int h = bid - 160;
    float* red = sh;
    float* fqv = sh + 512;
    float* fkv = sh + 576;
    float* pred = sh + 640;
    int cl = tid & 63, part4 = tid >> 6;
    float sq = 0.f, sk = 0.f;
#pragma unroll
    for (int p = 0; p < 16; ++p) {
      sq += gp[(size_t)(part4 * 16 + p) * 512 + h * 64 + cl];
      sk += gp[(size_t)(64 + part4 * 16 + p) * 512 + h * 64 + cl];
    }
    red[part4 * 128 + cl] = sq;
    red[part4 * 128 + 64 + cl] = sk;
    __syncthreads();
    if (tid < 128) {
      float vsum = red[tid] + red[128 + tid] + red[256 + tid] + red[384 + tid];
      if (tid < 64) fqv[tid] = vsum * (1.f / 4096.f);
      else          fkv[tid - 64] = vsum * (1.f / 4096.f);
    }
    __syncthreads();
    int j = tid & 63;
    float pp = 0.f;
#pragma unroll
    for (int i = 0; i < 16; ++i) {
      pp += fqv[part4 * 16 + i] * W1[j * 128 + part4 * 16 + i];
      pp += fkv[part4 * 16 + i] * W1[j * 128 + 64 + part4 * 16 + i];
    }
    pred[part4 * 64 + j] = pp;
    __syncthreads();
    if (tid < 64) {
      float pre = b1[j] + pred[j] + pred[64 + j] + pred[128 + j] + pred[192 + j];
      float s = wred_sum(pre);
      float ss = wred_sum(pre * pre);
      float mean = s * (1.f / 64.f);
      float var = ss * (1.f / 64.f) - mean * mean;
      float hdn = (pre - mean) * rsqrtf(var + LN_EPS) * lg[j] + lb[j];
      hdn = fmaxf(hdn, 0.f);
      float l0 = wred_sum(hdn * W2[0 * 64 + j]) + b2[0];
      float l1 = wred_sum(hdn * W2[1 * 64 + j]) + b2[1];
      float l2 = wred_sum(hdn * W2[2 * 64 + j]) + b2[2];
      float mx = fmaxf(l0, fmaxf(l1, l2));
      float e0 = __expf(l0 - mx), e1 = __expf(l1 - mx), e2 = __expf(l2 - mx);
      float inv = 1.f / (e0 + e1 + e2);
      if (j == 0) {
        wts[h * 3 + 0] = e0 * inv;
        wts[h * 3 + 1] = e1 * inv;
        wts[h * 3 + 2] = e2 * inv;
      }
    }
  }
}

// ---- apply: out = w0*qrn*(Q@Ahat^T) + f1*(Q@Apl^T) + rank1 ------------------
__global__ __launch_bounds__(256) void apply_kernel(
    const bf16* __restrict__ f_q, const float* __restrict__ Gpart,
    const float* __restrict__ rn, const float* __restrict__ mn,
    const float* __restrict__ vr, const float* __restrict__ wts,
    const float* __restrict__ kvm, const float* __restrict__ kvv,
    bf16* __restrict__ attnb) {
  __shared__ bf16 Qs[64 * 72];
  __shared__ bf16 Ap[64 * 72];
  __shared__ bf16 Ah[64 * 72];
  __shared__ float qrnL[64], qmnL[64], qvrL[64], kvmL[64], kvvL[64];
  // 512 = 8 x 64; same-hbid blocks share one XCD (Gpart L2 reuse)
  int lin = (blockIdx.x & 7) * 64 + (blockIdx.x >> 3);
  int hbid = lin >> 4, qt = lin & 15;
  int h = hbid >> 2, b = hbid & 3;
  int tid = threadIdx.x;
  int wv = tid >> 6, l = tid & 63, fr = l & 15, lq = l >> 4;
  {
    int row = tid >> 2, qq = (tid & 3) * 16;
    const bf16* qsrc = f_q + (size_t)(b * 1024 + qt * 64 + row) * 512 + h * 64 + qq;
    *(short8v*)&Qs[row * 72 + qq] = *(const short8v*)qsrc;
    *(short8v*)&Qs[row * 72 + qq + 8] = *(const short8v*)(qsrc + 8);
    const float* psrc = Gpart + (size_t)hbid * 32768 + row * 64 + qq;
#pragma unroll
    for (int c = 0; c < 4; ++c) {
      float4 spl = {0.f, 0.f, 0.f, 0.f}, sht = {0.f, 0.f, 0.f, 0.f};
#pragma unroll
      for (int mc = 0; mc < 4; ++mc) {
        float4 p = *(const float4*)(psrc + mc * 8192 + c * 4);
        float4 t = *(const float4*)(psrc + mc * 8192 + 4096 + c * 4);
        spl.x += p.x; spl.y += p.y; spl.z += p.z; spl.w += p.w;
        sht.x += t.x; sht.y += t.y; sht.z += t.z; sht.w += t.w;
      }
      Ap[row * 72 + qq + c * 4 + 0] = __float2bfloat16(spl.x);
      Ap[row * 72 + qq + c * 4 + 1] = __float2bfloat16(spl.y);
      Ap[row * 72 + qq + c * 4 + 2] = __float2bfloat16(spl.z);
      Ap[row * 72 + qq + c * 4 + 3] = __float2bfloat16(spl.w);
      Ah[row * 72 + qq + c * 4 + 0] = __float2bfloat16(sht.x);
      Ah[row * 72 + qq + c * 4 + 1] = __float2bfloat16(sht.y);
      Ah[row * 72 + qq + c * 4 + 2] = __float2bfloat16(sht.z);
      Ah[row * 72 + qq + c * 4 + 3] = __float2bfloat16(sht.w);
    }
  }
  if (tid < 64) {
    qrnL[tid] = rn[(size_t)hbid * 1024 + qt * 64 + tid];
    qmnL[tid] = mn[(size_t)hbid * 1024 + qt * 64 + tid];
    qvrL[tid] = vr[(size_t)hbid * 1024 + qt * 64 + tid];
    kvmL[tid] = kvm[hbid * 64 + tid];
    kvvL[tid] = kvv[hbid * 64 + tid];
  }
  __syncthreads();
  f32x4 ap_[4], ah_[4];
#pragma unroll
  for (int j = 0; j < 4; ++j)
#pragma unroll
    for (int e = 0; e < 4; ++e) { ap_[j][e] = 0.f; ah_[j][e] = 0.f; }
#pragma unroll
  for (int kk = 0; kk < 64; kk += 32) {
    short8v aq = *(const short8v*)&Qs[(wv * 16 + fr) * 72 + kk + lq * 8];
#pragma unroll
    for (int j = 0; j < 4; ++j) {
      short8v bp = *(const short8v*)&Ap[(j * 16 + fr) * 72 + kk + lq * 8];
      short8v bh = *(const short8v*)&Ah[(j * 16 + fr) * 72 + kk + lq * 8];
      ap_[j] = __builtin_amdgcn_mfma_f32_16x16x32_bf16(aq, bp, ap_[j], 0, 0, 0);
      ah_[j] = __builtin_amdgcn_mfma_f32_16x16x32_bf16(aq, bh, ah_[j], 0, 0, 0);
    }
  }
  float w0 = wts[h * 3 + 0], w1 = wts[h * 3 + 1], w2 = wts[h * 3 + 2];
  float f1 = w1 * (1.f / 64.f), w264 = w2 * (1.f / 64.f);
#pragma unroll
  for (int j = 0; j < 4; ++j) {
    int dv = j * 16 + fr;
    float km = kvmL[dv], kv2 = kvvL[dv];
#pragma unroll
    for (int rr = 0; rr < 4; ++rr) {
      int n = wv * 16 + lq * 4 + rr;
      float o = w0 * qrnL[n] * ah_[j][rr] + f1 * ap_[j][rr]
              - w1 * qmnL[n] * km + w264 * qvrL[n] * kv2;
      attnb[(size_t)(b * 1024 + qt * 64 + n) * 512 + h * 64 + dv] = __float2bfloat16(o);
    }
  }
}

extern "C" void kernel_launch(void* const* d_in, const int* in_sizes, int n_in,
                              void* d_out, int out_size, void* d_ws, size_t ws_size,
                              hipStream_t stream) {
  const float* q     = (const float*)d_in[0];
  const float* k     = (const float*)d_in[1];
  const float* v     = (const float*)d_in[2];
  const float* ln_g  = (const float*)d_in[3];
  const float* ln_b  = (const float*)d_in[4];
  const float* W_in  = (const float*)d_in[5];
  const float* W_out = (const float*)d_in[6];
  const float* b_out = (const float*)d_in[7];
  const float* wp_W1 = (const float*)d_in[8];
  const float* wp_b1 = (const float*)d_in[9];
  const float* wp_lg = (const float*)d_in[10];
  const float* wp_lb = (const float*)d_in[11];
  const float* wp_W2 = (const float*)d_in[12];
  const float* wp_b2 = (const float*)d_in[13];
  float* out = (float*)d_out;

  char* w8 = (char*)d_ws;
  bf16* abf   = (bf16*)(w8);                              // 12 MB (dead after proj)
  float* Gpart = (float*)(w8);                            // 4 MB, aliases abf
  bf16* f_q   = (bf16*)(w8 + (12u << 20));                // 4 MB
  bf16* fkt   = (bf16*)(w8 + (16u << 20));                // 4 MB
  bf16* fvt   = (bf16*)(w8 + (24u << 20));                // 4 MB
  bf16* attnb = (bf16*)(w8 + (28u << 20));                // 4 MB
  bf16* Wib   = (bf16*)(w8 + (32u << 20));                // 512 KB
  bf16* Wob   = (bf16*)(w8 + (32u << 20) + (512u << 10)); // 512 KB
  float* fb   = (float*)(w8 + (33u << 20));
  float* rn  = fb;            // 32768
  float* mn  = fb + 32768;    // 65536 (q, k)
  float* vr  = fb + 98304;    // 65536
  float* gp  = fb + 163840;   // 65536 ([2*64][512])
  float* kvm = fb + 229376;   // 2048
  float* kvv = fb + 231424;   // 2048
  float* wts = fb + 233472;   // 24

  lncvt_kernel<<<3200, 256, 0, stream>>>(q, k, v, ln_g, ln_b, W_in, W_out,
                                         abf, Wib, Wob);
  proj_kernel<<<768, 256, 0, stream>>>(
      abf, Wib, f_q, fkt, fvt, rn, mn, vr, gp);
  aux_kernel<<<168, 256, 0, stream>>>(
      fvt, fkt, mn, vr, gp, wp_W1, wp_b1, wp_lg, wp_lb, wp_W2, wp_b2,
      Gpart, kvm, kvv, wts);
  apply_kernel<<<512, 256, 0, stream>>>(
      f_q, Gpart, rn, mn, vr, wts, kvm, kvv, attnb);
  outproj_kernel<<<256, 256, 0, stream>>>(attnb, Wob, b_out, out);
}